// Round 10
// baseline (807.932 us; speedup 1.0000x reference)
//
#include <hip/hip_runtime.h>
#include <stdint.h>

typedef unsigned short u16;
typedef __attribute__((ext_vector_type(8))) short s16x8;
typedef __attribute__((ext_vector_type(4))) short s16x4;
typedef __attribute__((ext_vector_type(4))) float f32x4;

#define DEVFN static __device__ __forceinline__

static constexpr int NN = 20000;   // nodes
static constexpr int EE = 160000;  // edges (without self loops)
static constexpr int ET = 180000;  // edges + self loops
static constexpr int DD = 3000;    // input features
static constexpr int HH = 512;     // hidden
static constexpr int ZZ = 50;      // latent
static constexpr int C1 = 1536;    // HEADS*HH
static constexpr int C2 = 150;     // HEADS*ZZ
static constexpr int KP1 = 3072;   // GEMM1 K padded to x128 (B zero rows, A zero-filled)

DEVFN u16 f2b(float f) {
  uint32_t u = __builtin_bit_cast(uint32_t, f);
  u += 0x7FFFu + ((u >> 16) & 1u);   // RNE
  return (u16)(u >> 16);
}
DEVFN float b2f(u16 b) {
  uint32_t u = ((uint32_t)b) << 16;
  return __builtin_bit_cast(float, u);
}
DEVFN int edge_at(const void* ei, int mode32, long idx) {
  return mode32 ? ((const int*)ei)[idx] : (int)((const long long*)ei)[idx];
}

// async global->LDS, 16B per lane: lane i lands at (uniform base) + i*16.
typedef __attribute__((address_space(1))) const unsigned int gas_uint;
typedef __attribute__((address_space(3))) unsigned int las_uint;
DEVFN void async16(const u16* g, u16* l) {
  __builtin_amdgcn_global_load_lds((gas_uint*)(uintptr_t)g,
                                   (las_uint*)(unsigned)(uintptr_t)l, 16, 0, 0);
}

// in-block edge_index dtype sniff (int64 => odd 32b words of first 1024 all 0)
DEVFN int sniff_mode(const void* ei, int* nzsh) {
  if (threadIdx.x == 0) *nzsh = 0;
  __syncthreads();
  const int* e32 = (const int*)ei;
  int loc = 0;
  for (int i = threadIdx.x; i < 1024; i += blockDim.x)
    if (e32[2 * i + 1] != 0) loc = 1;
  if (loc) atomicOr(nzsh, 1);
  __syncthreads();
  return *nzsh;   // 1 = int32, 0 = int64
}

// ---------------- CSR build over dst ---------------------------------------
__global__ void k_deg(const void* ei, int* __restrict__ deg) {
  __shared__ int nz;
  int m = sniff_mode(ei, &nz);
  long i = (long)blockIdx.x * blockDim.x + threadIdx.x;
  long st = (long)gridDim.x * blockDim.x;
  for (; i < ET; i += st) {
    int d = (i < EE) ? edge_at(ei, m, EE + i) : (int)(i - EE);
    if ((unsigned)d < (unsigned)NN) atomicAdd(&deg[d], 1);
  }
}

__global__ void k_scan_blk(int* __restrict__ deg, int* __restrict__ rowptr,
                           int* __restrict__ bsum) {
  __shared__ int buf[256];
  int b = blockIdx.x, tid = threadIdx.x;
  int i = b * 256 + tid;
  buf[tid] = (i < NN) ? deg[i] : 0;
  if (i < NN) deg[i] = 0;
  __syncthreads();
  for (int off = 1; off < 256; off <<= 1) {
    int t = (tid >= off) ? buf[tid - off] : 0;
    __syncthreads();
    buf[tid] += t;
    __syncthreads();
  }
  if (i < NN) rowptr[i + 1] = buf[tid];
  if (tid == 255) bsum[b] = buf[255];
}
__global__ void k_scan_top(int* __restrict__ bsum, int nb) {
  __shared__ int buf[128];
  int tid = threadIdx.x;
  buf[tid] = (tid < nb) ? bsum[tid] : 0;
  __syncthreads();
  for (int off = 1; off < 128; off <<= 1) {
    int t = (tid >= off) ? buf[tid - off] : 0;
    __syncthreads();
    buf[tid] += t;
    __syncthreads();
  }
  if (tid < nb) bsum[tid] = buf[tid];
}
__global__ void k_scan_add(int* __restrict__ rowptr, const int* __restrict__ bsum) {
  int b = blockIdx.x, tid = threadIdx.x;
  int i = b * 256 + tid;
  if (i == 0) rowptr[0] = 0;
  if (b > 0 && i < NN) rowptr[i + 1] += bsum[b - 1];
}

__global__ void k_fill(const void* ei, const int* __restrict__ rowptr,
                       int* __restrict__ cursor, int* __restrict__ srcp) {
  __shared__ int nz;
  int m = sniff_mode(ei, &nz);
  long i = (long)blockIdx.x * blockDim.x + threadIdx.x;
  long st = (long)gridDim.x * blockDim.x;
  for (; i < ET; i += st) {
    int s, d;
    if (i < EE) { s = edge_at(ei, m, i); d = edge_at(ei, m, EE + i); }
    else { s = d = (int)(i - EE); }
    if ((unsigned)d < (unsigned)NN && (unsigned)s < (unsigned)NN) {
      int pos = atomicAdd(&cursor[d], 1);
      srcp[rowptr[d] + pos] = s;
    }
  }
}

// ---------------- converts -------------------------------------------------
__global__ void k_cvt_pad4(const float* __restrict__ in, u16* __restrict__ out,
                           int R, int Cin, int ldo) {
  int r = blockIdx.y;
  int c = (blockIdx.x * blockDim.x + threadIdx.x) * 4;
  if (c >= ldo) return;
  s16x4 o;
  const float* src = in + (size_t)r * Cin + c;
  if (r < R && c + 4 <= Cin && ((((size_t)r * Cin + c) & 3) == 0)) {
    f32x4 v = *(const f32x4*)src;
#pragma unroll
    for (int j = 0; j < 4; j++) o[j] = (short)f2b(v[j]);
  } else {
#pragma unroll
    for (int j = 0; j < 4; j++)
      o[j] = (short)((r < R && c + j < Cin) ? f2b(src[j]) : (u16)0);
  }
  *(s16x4*)(out + (size_t)r * ldo + c) = o;
}

__global__ void k_transpose_tile(const float* __restrict__ in, u16* __restrict__ out,
                                 int R, int Cc, int ldo) {
  __shared__ float t[32][33];
  int tx = threadIdx.x & 31, ty = threadIdx.x >> 5;   // 32x8
  int c0 = blockIdx.x * 32, r0 = blockIdx.y * 32;
#pragma unroll
  for (int j = 0; j < 4; j++) {
    int r = r0 + ty + j * 8, c = c0 + tx;
    t[ty + j * 8][tx] = (r < R && c < Cc) ? in[(size_t)r * Cc + c] : 0.f;
  }
  __syncthreads();
#pragma unroll
  for (int j = 0; j < 4; j++) {
    int c = c0 + ty + j * 8, r = r0 + tx;
    if (c < Cc && r < ldo) out[(size_t)c * ldo + r] = f2b(t[tx][ty + j * 8]);
  }
}

__global__ void k_transpose_cvt2(const float* __restrict__ in, u16* __restrict__ out,
                                 int R, int C, int Cp, int ldo) {
  long total = (long)Cp * ldo;
  long i = (long)blockIdx.x * blockDim.x + threadIdx.x;
  long st = (long)gridDim.x * blockDim.x;
  for (; i < total; i += st) {
    int c = (int)(i / ldo), r = (int)(i % ldo);
    out[i] = (c < C && r < R) ? f2b(in[(size_t)r * C + c]) : (u16)0;
  }
}

// ============ 8-phase 256x256 bf16 MFMA GEMM (T1..T5) ======================
// A_F32=false: A staged via global_load_lds (bf16), counted vmcnt(4).
// A_F32=true : fused f32->bf16 A staging.  KEY FIX vs r9: BOTH A half-tiles
//   (8 f32x4) are loaded in ph3 BEFORE the S3/S4 async16s, so consuming ra
//   next group costs vmcnt(4) (B prefetch stays in flight), never vmcnt(0).
//   Explicit vmcnt(12) at group start (before RDB8) forces this buffer's B
//   (issued >=1 group earlier) landed while leaving prev group's 8 A-loads
//   + 4 SBs outstanding.
template<bool OUT_BF16, bool RELU, bool A_F32>
__global__ __launch_bounds__(512, 2) void k_gemm8(
    const u16* __restrict__ Ag, const u16* __restrict__ Bg, void* __restrict__ Cg,
    const float* __restrict__ bias, int M, int Nn, int Kp, int lda, int ldb, int ldc,
    int Kreal) {
  __shared__ __align__(16) u16 As[2][256][64];   // 64 KB
  __shared__ __align__(16) u16 Bs[2][256][64];   // 64 KB
  int tid = threadIdx.x;
  int lane = tid & 63, wid = tid >> 6;
  int wm = wid >> 2, wn = wid & 3;               // 2 x 4 waves
  int lr = lane & 15, lg = lane >> 4;
  int rx = lr & 7;

  // T1 bijective XCD swizzle
  int nwg = gridDim.x * gridDim.y;
  int wg = blockIdx.y * gridDim.x + blockIdx.x;
  int q = nwg >> 3, r = nwg & 7;
  int xcd = wg & 7, loc = wg >> 3;
  int swz = (xcd < r ? xcd * (q + 1) : r * (q + 1) + (xcd - r) * q) + loc;
  int m0 = (swz / gridDim.x) * 256, n0 = (swz % gridDim.x) * 256;

  int srow = tid >> 3;
  int schunk = ((tid & 7) ^ (srow & 7)) * 8;     // inverse-swizzled source chunk
  const u16* agp[4];
  const float* agf[4];
  const u16* bgp[4];
  const float* Af = (const float*)Ag;
#pragma unroll
  for (int i = 0; i < 4; i++) {
    int ra_ = i * 64 + srow;
    int ga = m0 + ra_; if (ga > M - 1) ga = M - 1;
    agp[i] = Ag + (size_t)ga * lda + schunk;
    agf[i] = Af + (size_t)ga * lda + schunk;
    bgp[i] = Bg + (size_t)(n0 + ra_) * ldb + schunk;
  }
  u16* aB0 = &As[0][0][0]; u16* aB1 = &As[1][0][0];
  u16* bB0 = &Bs[0][0][0]; u16* bB1 = &Bs[1][0][0];

#define SA(cb, h, kt) do {                                                  \
    u16* d_ = ((cb) ? aB1 : aB0);                                           \
    async16(agp[2*(h)]   + (size_t)(kt)*64, d_ + (2*(h))*4096 + wid*512);   \
    async16(agp[2*(h)+1] + (size_t)(kt)*64, d_ + (2*(h)+1)*4096 + wid*512); \
  } while (0)
#define SB(cb, h, kt) do {                                                  \
    u16* d_ = ((cb) ? bB1 : bB0);                                           \
    async16(bgp[2*(h)]   + (size_t)(kt)*64, d_ + (2*(h))*4096 + wid*512);   \
    async16(bgp[2*(h)+1] + (size_t)(kt)*64, d_ + (2*(h)+1)*4096 + wid*512); \
  } while (0)
#define BARX() do { asm volatile("" ::: "memory");                          \
    __builtin_amdgcn_s_barrier(); asm volatile("" ::: "memory"); } while (0)
#define VMC(n) asm volatile("s_waitcnt vmcnt(" #n ")" ::: "memory")
#define RDA(dst, cb, mi, ks) dst = *(const s16x8*)&As[cb][wm*128+(mi)*16+lr][(((ks)*4+lg)^rx)*8]
#define RDB(dst, cb, ni, ks) dst = *(const s16x8*)&Bs[cb][wn*64+(ni)*16+lr][(((ks)*4+lg)^rx)*8]

  f32x4 acc[8][4];
#pragma unroll
  for (int mi = 0; mi < 8; mi++)
#pragma unroll
    for (int ni = 0; ni < 4; ni++) {
      acc[mi][ni][0] = 0.f; acc[mi][ni][1] = 0.f;
      acc[mi][ni][2] = 0.f; acc[mi][ni][3] = 0.f;
    }

  s16x8 bfr[2][4];        // B frags: ks x ni (whole group)
  s16x8 f0[4], f1[4];     // A frags ping-pong (bf16 path)
  s16x8 fs[4];            // A frags single set (f32 path)
  f32x4 ra[8];            // staged f32 A: BOTH half-tiles (h*4 + 2*j + w)

  // load both A half-tiles of tile kt into ra (8 x f32x4; zero-fill >= Kreal)
#define LOADA8(kt) do {                                                 \
    int kk_ = (kt) * 64 + schunk;                                       \
    _Pragma("unroll")                                                   \
    for (int h_ = 0; h_ < 2; h_++)                                      \
    _Pragma("unroll")                                                   \
    for (int j_ = 0; j_ < 2; j_++) {                                    \
      const float* p_ = agf[2*h_+j_] + (size_t)(kt) * 64;               \
      if (kk_ + 8 <= Kreal) {                                           \
        ra[h_*4+2*j_]   = *(const f32x4*)p_;                            \
        ra[h_*4+2*j_+1] = *(const f32x4*)(p_ + 4);                      \
      } else {                                                          \
        _Pragma("unroll")                                               \
        for (int e_ = 0; e_ < 4; e_++) {                                \
          ra[h_*4+2*j_][e_]   = (kk_ + e_     < Kreal) ? p_[e_]     : 0.f; \
          ra[h_*4+2*j_+1][e_] = (kk_ + 4 + e_ < Kreal) ? p_[e_ + 4] : 0.f; \
        }                                                               \
      }                                                                 \
    } } while (0)
  // cvt+write half-tile h of ra into buf's A region (linear LDS, swizzled src)
#define CVTW_F(buf, h) do {                                             \
    u16* d_ = ((buf) ? aB1 : aB0);                                      \
    _Pragma("unroll")                                                   \
    for (int j_ = 0; j_ < 2; j_++) {                                    \
      s16x8 o_;                                                         \
      _Pragma("unroll")                                                 \
      for (int e_ = 0; e_ < 4; e_++) {                                  \
        o_[e_]     = (short)f2b(ra[(h)*4+2*j_][e_]);                    \
        o_[e_ + 4] = (short)f2b(ra[(h)*4+2*j_+1][e_]);                  \
      }                                                                 \
      *(s16x8*)(d_ + (2*(h)+j_)*4096 + tid*8) = o_;                     \
    } } while (0)

#define RDB8(cb) do {                                                   \
    RDB(bfr[0][0], cb, 0, 0); RDB(bfr[0][1], cb, 1, 0);                 \
    RDB(bfr[0][2], cb, 2, 0); RDB(bfr[0][3], cb, 3, 0);                 \
    RDB(bfr[1][0], cb, 0, 1); RDB(bfr[1][1], cb, 1, 1);                 \
    RDB(bfr[1][2], cb, 2, 1); RDB(bfr[1][3], cb, 3, 1); } while (0)
#define RDAP(F, cb, P) do {                                             \
    RDA(F[0], cb, 2*(P), 0);   RDA(F[1], cb, 2*(P), 1);                 \
    RDA(F[2], cb, 2*(P)+1, 0); RDA(F[3], cb, 2*(P)+1, 1); } while (0)
#define DO_MFMA(P, F) do {                                              \
    _Pragma("unroll")                                                   \
    for (int ni_ = 0; ni_ < 4; ni_++) {                                 \
      acc[2*(P)][ni_]   = __builtin_amdgcn_mfma_f32_16x16x32_bf16(F[0], bfr[0][ni_], acc[2*(P)][ni_], 0, 0, 0);   \
      acc[2*(P)][ni_]   = __builtin_amdgcn_mfma_f32_16x16x32_bf16(F[1], bfr[1][ni_], acc[2*(P)][ni_], 0, 0, 0);   \
      acc[2*(P)+1][ni_] = __builtin_amdgcn_mfma_f32_16x16x32_bf16(F[2], bfr[0][ni_], acc[2*(P)+1][ni_], 0, 0, 0); \
      acc[2*(P)+1][ni_] = __builtin_amdgcn_mfma_f32_16x16x32_bf16(F[3], bfr[1][ni_], acc[2*(P)+1][ni_], 0, 0, 0); \
    } } while (0)

// bf16-A group (lin2): one barrier per phase + VMC(4) at group end (r8 form)
#define GROUP(cb, S1, S2, S3, S4) do {                                  \
    RDB8(cb); RDAP(f0, cb, 0);                                          \
    S1; BARX();                                                         \
    __builtin_amdgcn_s_setprio(1);                                      \
    RDAP(f1, cb, 1); DO_MFMA(0, f0);                                    \
    __builtin_amdgcn_s_setprio(0);                                      \
    S2; BARX();                                                         \
    __builtin_amdgcn_s_setprio(1);                                      \
    RDAP(f0, cb, 2); DO_MFMA(1, f1);                                    \
    __builtin_amdgcn_s_setprio(0);                                      \
    S3; BARX();                                                         \
    __builtin_amdgcn_s_setprio(1);                                      \
    RDAP(f1, cb, 3); DO_MFMA(2, f0);                                    \
    __builtin_amdgcn_s_setprio(0);                                      \
    S4; BARX();                                                         \
    __builtin_amdgcn_s_setprio(1);                                      \
    DO_MFMA(3, f1);                                                     \
    __builtin_amdgcn_s_setprio(0); VMC(4); BARX();                      \
  } while (0)

// f32-A group (fixed): ph1 CVTW(h0)  [vmcnt(4) — 4 SBs issued after ra];
// ph2 CVTW(h1); ph3 LOADA8(next A) THEN S3; ph4 S4.  Group-start VMC(12)
// (before RDB8) forces this buffer's B landed; leaves prev {8 A-loads,
// 4 SBs} in flight.
#define GROUPF(cb, ktAn, S3, S4) do {                                   \
    VMC(12);                                                            \
    RDB8(cb);                                                           \
    CVTW_F((cb) ^ 1, 0);                                                \
    RDAP(fs, cb, 0);                                                    \
    BARX();                                                             \
    __builtin_amdgcn_s_setprio(1); DO_MFMA(0, fs);                      \
    __builtin_amdgcn_s_setprio(0);                                      \
    CVTW_F((cb) ^ 1, 1);                                                \
    RDAP(fs, cb, 1);                                                    \
    BARX();                                                             \
    __builtin_amdgcn_s_setprio(1); DO_MFMA(1, fs);                      \
    __builtin_amdgcn_s_setprio(0);                                      \
    LOADA8(ktAn);                                                       \
    S3;                                                                 \
    RDAP(fs, cb, 2);                                                    \
    BARX();                                                             \
    __builtin_amdgcn_s_setprio(1); DO_MFMA(2, fs);                      \
    __builtin_amdgcn_s_setprio(0);                                      \
    S4;                                                                 \
    RDAP(fs, cb, 3);                                                    \
    BARX();                                                             \
    __builtin_amdgcn_s_setprio(1); DO_MFMA(3, fs);                      \
    __builtin_amdgcn_s_setprio(0); BARX();                              \
  } while (0)

  int nt = Kp >> 6;   // even, >= 2
  if constexpr (A_F32) {
    // prologue: buf0 B; buf0 A (reg-staged, drains — one-time);
    // ra := A(tile1) loaded BEFORE buf1's B SBs (so loop waits are vmcnt(4)).
    SB(0, 0, 0); SB(0, 1, 0);
    LOADA8(0); CVTW_F(0, 0); CVTW_F(0, 1);
    int k1 = 1 < nt ? 1 : nt - 1;
    LOADA8(k1);
    SB(1, 0, k1); SB(1, 1, k1);
    asm volatile("s_waitcnt lgkmcnt(0)" ::: "memory");
    BARX();
    for (int t = 0; t < nt; t += 2) {
      int t2 = (t + 2 < nt) ? t + 2 : nt - 1;
      int t3 = (t + 3 < nt) ? t + 3 : nt - 1;
      GROUPF(0, t2, SB(0, 0, t2), SB(0, 1, t2));   // CVTW: A(t+1)->buf1
      GROUPF(1, t3, SB(1, 0, t3), SB(1, 1, t3));   // CVTW: A(t2) ->buf0
    }
  } else {
    SB(0, 0, 0); SB(0, 1, 0);
    SA(0, 0, 0); SA(0, 1, 0);
    { int k1 = 1 < nt ? 1 : nt - 1; SB(1, 0, k1); SB(1, 1, k1); }
    VMC(4);
    BARX();
    for (int t = 0; t < nt; t += 2) {
      int t2 = (t + 2 < nt) ? t + 2 : nt - 1;
      int t3 = (t + 3 < nt) ? t + 3 : nt - 1;
      GROUP(0, SA(1, 0, t + 1), SA(1, 1, t + 1), SB(0, 0, t2), SB(0, 1, t2));
      GROUP(1, SA(0, 0, t2),    SA(0, 1, t2),    SB(1, 0, t3), SB(1, 1, t3));
    }
  }
  asm volatile("s_waitcnt vmcnt(0)" ::: "memory");

#undef SA
#undef SB
#undef BARX
#undef VMC
#undef RDA
#undef RDB
#undef RDB8
#undef RDAP
#undef DO_MFMA
#undef GROUP
#undef GROUPF
#undef LOADA8
#undef CVTW_F

  // epilogue: D col=lane&15, row=(lane>>4)*4+reg   [m89-verified]
#pragma unroll
  for (int mi = 0; mi < 8; mi++)
#pragma unroll
    for (int ni = 0; ni < 4; ni++) {
      int col = n0 + wn * 64 + ni * 16 + lr;
      if (col >= Nn) continue;
      float bv = bias ? bias[col] : 0.f;
#pragma unroll
      for (int j = 0; j < 4; j++) {
        int row = m0 + wm * 128 + mi * 16 + lg * 4 + j;
        if (row >= M) continue;
        float v = acc[mi][ni][j] + bv;
        if (RELU) v = v > 0.f ? v : 0.f;
        if (OUT_BF16) ((u16*)Cg)[(size_t)row * ldc + col] = f2b(v);
        else          ((float*)Cg)[(size_t)row * ldc + col] = v;
      }
    }
}

// ---------------- 128x128 2-phase GEMM (small shapes: GEMM2, lin1) ---------
template<bool OUT_BF16, bool RELU>
__global__ __launch_bounds__(256) void k_gemm3(
    const u16* __restrict__ Ag, const u16* __restrict__ Bg, void* __restrict__ Cg,
    const float* __restrict__ bias, int M, int Nn, int Kp, int ld, int ldc) {
  __shared__ __align__(16) u16 As[2][128][64];
  __shared__ __align__(16) u16 Bs[2][128][64];
  int tid = threadIdx.x;
  int lane = tid & 63, wid = tid >> 6;
  int wm = wid >> 1, wn = wid & 1;
  int lr = lane & 15, lg = lane >> 4;

  int nwg = gridDim.x * gridDim.y;
  int wg = blockIdx.y * gridDim.x + blockIdx.x;
  int q = nwg >> 3, r = nwg & 7;
  int xcd = wg & 7, loc = wg >> 3;
  int swz = (xcd < r ? xcd * (q + 1) : r * (q + 1) + (xcd - r) * q) + loc;
  int m0 = (swz / gridDim.x) * 128, n0 = (swz % gridDim.x) * 128;

  int srow = lane >> 3;
  int skk = ((lane & 7) ^ srow) * 8;
  const u16* agp[4];
  const u16* bgp[4];
#pragma unroll
  for (int i = 0; i < 4; i++) {
    int ra = wid * 32 + i * 8 + srow;
    int ga = m0 + ra; if (ga > M - 1) ga = M - 1;
    agp[i] = Ag + (size_t)ga * ld + skk;
    bgp[i] = Bg + (size_t)(n0 + ra) * ld + skk;
  }

#define STAGE(bufi, kofs) do {                                   \
    u16* la_ = &As[bufi][0][0] + wid * 2048;                     \
    u16* lb_ = &Bs[bufi][0][0] + wid * 2048;                     \
    _Pragma("unroll")                                            \
    for (int i_ = 0; i_ < 4; i_++) {                             \
      async16(agp[i_] + (kofs), la_ + i_ * 512);                 \
      async16(bgp[i_] + (kofs), lb_ + i_ * 512);                 \
    }                                                            \
  } while (0)

  f32x4 acc[4][4];
#pragma unroll
  for (int mi = 0; mi < 4; mi++)
#pragma unroll
    for (int ni = 0; ni < 4; ni++) {
      acc[mi][ni][0] = 0.f; acc[mi][ni][1] = 0.f; acc[mi][ni][2] = 0.f; acc[mi][ni][3] = 0.f;
    }

  int rx = lr & 7;
  int NT = Kp >> 6;
  STAGE(0, 0);
  for (int t = 0; t < NT; t++) {
    int cur = t & 1;
    if (t + 1 < NT) {
      STAGE(cur ^ 1, (t + 1) * 64);
      asm volatile("s_waitcnt vmcnt(8)" ::: "memory");
    } else {
      asm volatile("s_waitcnt vmcnt(0)" ::: "memory");
    }
    __builtin_amdgcn_s_barrier();
    asm volatile("" ::: "memory");
#pragma unroll
    for (int ks = 0; ks < 2; ks++) {
      int ch = ((ks * 4 + lg) ^ rx) * 8;
      s16x8 a[4], b[4];
#pragma unroll
      for (int mi = 0; mi < 4; mi++)
        a[mi] = *(const s16x8*)&As[cur][wm * 64 + mi * 16 + lr][ch];
#pragma unroll
      for (int ni = 0; ni < 4; ni++)
        b[ni] = *(const s16x8*)&Bs[cur][wn * 64 + ni * 16 + lr][ch];
#pragma unroll
      for (int mi = 0; mi < 4; mi++)
#pragma unroll
        for (int ni = 0; ni < 4; ni++)
          acc[mi][ni] = __builtin_amdgcn_mfma_f32_16x16x32_bf16(a[mi], b[ni], acc[mi][ni], 0, 0, 0);
    }
    asm volatile("" ::: "memory");
    __builtin_amdgcn_s_barrier();
  }
#undef STAGE

#pragma unroll
  for (int mi = 0; mi < 4; mi++)
#pragma unroll
    for (int ni = 0; ni < 4; ni++) {
      int col = n0 + wn * 64 + ni * 16 + lr;
      if (col >= Nn) continue;
      float bv = bias ? bias[col] : 0.f;
#pragma unroll
      for (int j = 0; j < 4; j++) {
        int row = m0 + wm * 64 + mi * 16 + lg * 4 + j;
        if (row >= M) continue;
        float v = acc[mi][ni][j] + bv;
        if (RELU) v = v > 0.f ? v : 0.f;
        if (OUT_BF16) ((u16*)Cg)[(size_t)row * ldc + col] = f2b(v);
        else          ((float*)Cg)[(size_t)row * ldc + col] = v;
      }
    }
}

// ---------------- attention dot products -----------------------------------
__global__ void k_attdot1b(const u16* __restrict__ h1b, const float* __restrict__ asrc,
                           const float* __restrict__ adst, float* __restrict__ as_,
                           float* __restrict__ ad_, float* __restrict__ z0,
                           float* __restrict__ z1) {
  int n = blockIdx.x;
  if (n == 0) {
    for (int i = threadIdx.x; i < HH; i += 192) { z0[i] = 0.f; z1[i] = 0.f; }
  }
  int hd = threadIdx.x >> 6, lane = threadIdx.x & 63;
  s16x8 h = *(const s16x8*)(h1b + (size_t)n * C1 + hd * 512 + lane * 8);
  const float* ap = asrc + hd * 512 + lane * 8;
  const float* dp = adst + hd * 512 + lane * 8;
  f32x4 a0 = *(const f32x4*)ap, a1 = *(const f32x4*)(ap + 4);
  f32x4 d0 = *(const f32x4*)dp, d1 = *(const f32x4*)(dp + 4);
  float ps = 0.f, pd = 0.f;
#pragma unroll
  for (int j = 0; j < 4; j++) {
    float hv = b2f((u16)h[j]);
    ps += hv * a0[j]; pd += hv * d0[j];
    float hw = b2f((u16)h[j + 4]);
    ps += hw * a1[j]; pd += hw * d1[j];
  }
  for (int off = 32; off; off >>= 1) { ps += __shfl_xor(ps, off); pd += __shfl_xor(pd, off); }
  if (lane == 0) { as_[3 * n + hd] = ps; ad_[3 * n + hd] = pd; }
}

__global__ void k_attdot2(const float* __restrict__ s2, const float* __restrict__ asrc,
                          const float* __restrict__ adst, float* __restrict__ as_,
                          float* __restrict__ ad_, float* __restrict__ z0,
                          float* __restrict__ z1, float* __restrict__ z2,
                          float* __restrict__ z3) {
  int n = blockIdx.x, tid = threadIdx.x;
  if (n == 0) {
    for (int i = tid; i < HH; i += 64) { z2[i] = 0.f; z3[i] = 0.f; }
    if (tid < 50) { z0[tid] = 0.f; z1[tid] = 0.f; }
  }
  for (int hd = 0; hd < 3; hd++) {
    float ps = 0.f, pd = 0.f;
    if (tid < 50) {
      float v = s2[(size_t)n * C2 + hd * 50 + tid];
      ps = v * asrc[hd * 50 + tid];
      pd = v * adst[hd * 50 + tid];
    }
    for (int off = 32; off; off >>= 1) { ps += __shfl_xor(ps, off); pd += __shfl_xor(pd, off); }
    if (tid == 0) { as_[3 * n + hd] = ps; ad_[3 * n + hd] = pd; }
  }
}

// ---------------- GAT aggregation ------------------------------------------
__global__ __launch_bounds__(192) void k_gat1(
    const u16* __restrict__ h1b, const float* __restrict__ as1,
    const float* __restrict__ ad1, const int* __restrict__ rowptr,
    const int* __restrict__ srcp, const float* __restrict__ bias,
    float* __restrict__ out) {
  int n = blockIdx.x, tid = threadIdx.x;
  __shared__ float sm[3], sden[3];
  __shared__ int s_src[128];
  __shared__ float s_alpha[128][3];
  __shared__ float part[3][512];
  int r0 = rowptr[n], deg = rowptr[n + 1] - r0;
  float adl[3] = {ad1[3 * n], ad1[3 * n + 1], ad1[3 * n + 2]};

  if (tid < 64) {
    float mx[3] = {-1e30f, -1e30f, -1e30f};
    for (int e = tid; e < deg; e += 64) {
      int s = srcp[r0 + e];
#pragma unroll
      for (int hd = 0; hd < 3; hd++) {
        float v = as1[3 * s + hd] + adl[hd];
        v = v > 0.f ? v : 0.2f * v;
        mx[hd] = fmaxf(mx[hd], v);
      }
    }
#pragma unroll
    for (int hd = 0; hd < 3; hd++)
      for (int off = 32; off; off >>= 1) mx[hd] = fmaxf(mx[hd], __shfl_xor(mx[hd], off));
    float sd[3] = {0.f, 0.f, 0.f};
    for (int e = tid; e < deg; e += 64) {
      int s = srcp[r0 + e];
#pragma unroll
      for (int hd = 0; hd < 3; hd++) {
        float v = as1[3 * s + hd] + adl[hd];
        v = v > 0.f ? v : 0.2f * v;
        sd[hd] += __expf(v - mx[hd]);
      }
    }
#pragma unroll
    for (int hd = 0; hd < 3; hd++)
      for (int off = 32; off; off >>= 1) sd[hd] += __shfl_xor(sd[hd], off);
    if (tid == 0) {
#pragma unroll
      for (int hd = 0; hd < 3; hd++) { sm[hd] = mx[hd]; sden[hd] = sd[hd]; }
    }
  }
  __syncthreads();

  int hd = tid >> 6, lane = tid & 63;
  float a[8];
#pragma unroll
  for (int j = 0; j < 8; j++) a[j] = 0.f;

  for (int base = 0; base < deg; base += 128) {
    int cnt = min(128, deg - base);
    if (tid < cnt) {
      int s = srcp[r0 + base + tid];
      s_src[tid] = s;
#pragma unroll
      for (int h2 = 0; h2 < 3; h2++) {
        float v = as1[3 * s + h2] + adl[h2];
        v = v > 0.f ? v : 0.2f * v;
        s_alpha[tid][h2] = __expf(v - sm[h2]) / sden[h2];
      }
    }
    __syncthreads();
    int e = 0;
    for (; e + 2 <= cnt; e += 2) {
      const u16* p0 = h1b + (size_t)s_src[e] * C1 + (hd << 9) + lane * 8;
      const u16* p1 = h1b + (size_t)s_src[e + 1] * C1 + (hd << 9) + lane * 8;
      s16x8 v0 = *(const s16x8*)p0;
      s16x8 v1 = *(const s16x8*)p1;
      float al0 = s_alpha[e][hd], al1 = s_alpha[e + 1][hd];
#pragma unroll
      for (int j = 0; j < 8; j++)
        a[j] += al0 * b2f((u16)v0[j]) + al1 * b2f((u16)v1[j]);
    }
    if (e < cnt) {
      const u16* p0 = h1b + (size_t)s_src[e] * C1 + (hd << 9) + lane * 8;
      s16x8 v0 = *(const s16x8*)p0;
      float al0 = s_alpha[e][hd];
#pragma unroll
      for (int j = 0; j < 8; j++) a[j] += al0 * b2f((u16)v0[j]);
    }
    __syncthreads();
  }

#pragma unroll
  for (int j = 0; j < 8; j++) part[hd][lane * 8 + j] = a[j];
  __syncthreads();
  if (tid < 128) {
    f32x4 p0 = *(const f32x4*)&part[0][tid * 4];
    f32x4 p1 = *(const f32x4*)&part[1][tid * 4];
    f32x4 p2 = *(const f32x4*)&part[2][tid * 4];
    f32x4 bv = *(const f32x4*)(bias + tid * 4);
    f32x4 o;
#pragma unroll
    for (int j = 0; j < 4; j++) o[j] = (p0[j] + p1[j] + p2[j]) * (1.f / 3.f) + bv[j];
    *(f32x4*)(out + (size_t)n * 512 + tid * 4) = o;
  }
}

__global__ void k_gat2(const float* __restrict__ s2, const float* __restrict__ as2,
                       const float* __restrict__ ad2, const int* __restrict__ rowptr,
                       const int* __restrict__ srcp, const float* __restrict__ bias,
                       float* __restrict__ z) {
  int n = blockIdx.x, tid = threadIdx.x;
  __shared__ int s_src[64];
  __shared__ float s_alpha[64][3];
  int r0 = rowptr[n], deg = rowptr[n + 1] - r0;
  float adl[3] = {ad2[3 * n], ad2[3 * n + 1], ad2[3 * n + 2]};

  float mx[3] = {-1e30f, -1e30f, -1e30f};
  for (int e = tid; e < deg; e += 64) {
    int s = srcp[r0 + e];
#pragma unroll
    for (int hd = 0; hd < 3; hd++) {
      float v = as2[3 * s + hd] + adl[hd];
      v = v > 0.f ? v : 0.2f * v;
      mx[hd] = fmaxf(mx[hd], v);
    }
  }
#pragma unroll
  for (int hd = 0; hd < 3; hd++)
    for (int off = 32; off; off >>= 1) mx[hd] = fmaxf(mx[hd], __shfl_xor(mx[hd], off));
  float sd[3] = {0.f, 0.f, 0.f};
  for (int e = tid; e < deg; e += 64) {
    int s = srcp[r0 + e];
#pragma unroll
    for (int hd = 0; hd < 3; hd++) {
      float v = as2[3 * s + hd] + adl[hd];
      v = v > 0.f ? v : 0.2f * v;
      sd[hd] += __expf(v - mx[hd]);
    }
  }
#pragma unroll
  for (int hd = 0; hd < 3; hd++)
    for (int off = 32; off; off >>= 1) sd[hd] += __shfl_xor(sd[hd], off);

  float acc = 0.f;
  for (int base = 0; base < deg; base += 64) {
    int cnt = min(64, deg - base);
    if (tid < cnt) {
      int s = srcp[r0 + base + tid];
      s_src[tid] = s;
#pragma unroll
      for (int hd = 0; hd < 3; hd++) {
        float v = as2[3 * s + hd] + adl[hd];
        v = v > 0.f ? v : 0.2f * v;
        s_alpha[tid][hd] = __expf(v - mx[hd]) / sd[hd];
      }
    }
    __syncthreads();
    if (tid < 50) {
      for (int e = 0; e < cnt; e++) {
        const float* row = s2 + (size_t)s_src[e] * C2;
#pragma unroll
        for (int hd = 0; hd < 3; hd++) acc += s_alpha[e][hd] * row[hd * 50 + tid];
      }
    }
    __syncthreads();
  }
  if (tid < 50) z[(size_t)n * ZZ + tid] = acc * (1.f / 3.f) + bias[tid];
}

// ---------------- BatchNorm (training stats, biased var) -------------------
__global__ void k_colstats3(const float* __restrict__ x, float* __restrict__ gsum,
                            float* __restrict__ gsq, long total, int C) {
  long i = (long)blockIdx.x * blockDim.x + threadIdx.x;
  long st = (long)gridDim.x * blockDim.x;
  int c = (int)(i % C);
  float s = 0.f, q = 0.f;
  for (; i < total; i += st) { float v = x[i]; s += v; q += v * v; }
  atomicAdd(&gsum[c], s);
  atomicAdd(&gsq[c], q);
}

// fused bnfinal+bnrelu for C=512 (scale/shift recomputed from L2-hot sums)
__global__ void k_bnrelu4f(const float* __restrict__ x, const float* __restrict__ gsum,
                           const float* __restrict__ gsq, const float* __restrict__ g,
                           const float* __restrict__ bb, u16* __restrict__ out,
                           long total4, float invN) {
  long i = (long)blockIdx.x * blockDim.x + threadIdx.x;
  long st = (long)gridDim.x * blockDim.x;
  for (; i < total4; i += st) {
    long b = i * 4;
    int c = (int)(b & 511);
    f32x4 v = *(const f32x4*)(x + b);
    f32x4 s = *(const f32x4*)(gsum + c);
    f32x4 qv = *(const f32x4*)(gsq + c);
    f32x4 gg = *(const f32x4*)(g + c);
    f32x4 bv = *(const f32x4*)(bb + c);
    s16x4 o;
#pragma unroll
    for (int j = 0; j < 4; j++) {
      float m = s[j] * invN;
      float var = qv[j] * invN - m * m;
      float sc = gg[j] * rsqrtf(var + 1e-5f);
      float r = (v[j] - m) * sc + bv[j];
      r = r > 0.f ? r : 0.f;
      o[j] = (short)f2b(r);
    }
    *(s16x4*)(out + b) = o;
  }
}

// fused bnfinal + bnrelu + pad for the 50->64 latent (zb)
__global__ void k_bnrelu_padf(const float* __restrict__ x, const float* __restrict__ gsum,
                              const float* __restrict__ gsq, const float* __restrict__ g,
                              const float* __restrict__ bb, u16* __restrict__ out) {
  int i = blockIdx.x * blockDim.x + threadIdx.x;
  if (i >= NN * 64) return;
  int c = i & 63, r = i >> 6;
  float v = 0.f;
  if (c < 50) {
    float m = gsum[c] * (1.0f / NN);
    float var = gsq[c] * (1.0f / NN) - m * m;
    float sc = g[c] * rsqrtf(var + 1e-5f);
    v = (x[r * 50 + c] - m) * sc + bb[c];
    v = v > 0.f ? v : 0.f;
  }
  out[i] = f2b(v);
}

// ---------------------------------------------------------------------------
extern "C" void kernel_launch(void* const* d_in, const int* in_sizes, int n_in,
                              void* d_out, int out_size, void* d_ws, size_t ws_size,
                              hipStream_t stream) {
  (void)in_sizes; (void)n_in; (void)out_size;
  const float* x     = (const float*)d_in[0];
  const void*  ei    = d_in[1];
  const float* W1    = (const float*)d_in[2];
  const float* asrc1 = (const float*)d_in[3];
  const float* adst1 = (const float*)d_in[4];
  const float* b1    = (const float*)d_in[5];
  const float* bn1g  = (const float*)d_in[6];
  const float* bn1b  = (const float*)d_in[7];
  const float* W2    = (const float*)d_in[8];
  const float* asrc2 = (const float*)d_in[9];
  const float* adst2 = (const float*)d_in[10];
  const float* b2    = (const float*)d_in[11];
  const float* bn2g  = (const float*)d_in[12];
  const float* bn2b  = (const float*)d_in[13];
  const float* l1w   = (const float*)d_in[14];
  const float* l1b   = (const float*)d_in[15];
  const float* dbng  = (const float*)d_in[16];
  const float* dbnb  = (const float*)d_in[17];
  const float* l2w   = (const float*)d_in[18];
  const float* l2b   = (const float*)d_in[19];
  float* out = (float*)d_out;
  char* ws = (char*)d_ws;

  size_t off = 0;
  auto alloc = [&](size_t b) { size_t r = off; off += (b + 255) & ~(size_t)255; return r; };
  const size_t oXB  = alloc(120320000);                  // region reused: g1/h2b/s2/zf/zb/...
  const size_t oH1  = alloc(61440000);                   // h1b [20000][1536]; later db
  const size_t oW1T = alloc((size_t)C1 * KP1 * 2);       // w1T [1536][3072]
  const size_t oAS1 = alloc((size_t)NN * 12), oAD1 = alloc((size_t)NN * 12);
  const size_t oAS2 = alloc((size_t)NN * 12), oAD2 = alloc((size_t)NN * 12);
  const size_t oRP  = alloc((size_t)(NN + 1) * 4);
  const size_t oDEG = alloc((size_t)NN * 4);
  const size_t oSRC = alloc((size_t)ET * 4);
  const size_t oBSUM = alloc(512);
  const size_t oS1 = alloc(2048), oQ1 = alloc(2048);
  const size_t oS2 = alloc(2048), oQ2 = alloc(2048);
  const size_t oS3 = alloc(2048), oQ3 = alloc(2048);
  if (ws_size < off) return;

  float* g1   = (float*)(ws + oXB);
  u16*   h2b  = (u16*)(ws + oXB + 40960000);
  float* s2   = (float*)(ws + oXB + 61440000);
  float* zf   = (float*)(ws + oXB + 73440000);
  u16*   zb   = (u16*)(ws + oXB + 77440000);
  u16*   w2T  = (u16*)(ws + oXB + 80000000);
  u16*   l1wT = (u16*)(ws + oXB + 80262400);
  u16*   l2wT = (u16*)(ws + oXB + 80328192);
  float* dbuf = (float*)(ws + oXB);
  u16*   h1b  = (u16*)(ws + oH1);
  u16*   db   = (u16*)(ws + oH1);
  u16*   w1T  = (u16*)(ws + oW1T);
  int* bsum   = (int*)(ws + oBSUM);
  int* deg    = (int*)(ws + oDEG);
  int* rowptr = (int*)(ws + oRP);
  int* srcp   = (int*)(ws + oSRC);
  float *as1 = (float*)(ws + oAS1), *ad1 = (float*)(ws + oAD1);
  float *as2 = (float*)(ws + oAS2), *ad2 = (float*)(ws + oAD2);
  float *sum1 = (float*)(ws + oS1), *sq1 = (float*)(ws + oQ1);
  float *sum2 = (float*)(ws + oS2), *sq2 = (float*)(ws + oQ2);
  float *sum3 = (float*)(ws + oS3), *sq3 = (float*)(ws + oQ3);

  // --- CSR by dst (with self loops) ---
  hipMemsetAsync(deg, 0, (size_t)NN * 4, stream);
  k_deg<<<512, 256, 0, stream>>>(ei, deg);
  k_scan_blk<<<79, 256, 0, stream>>>(deg, rowptr, bsum);   // also zeroes deg
  k_scan_top<<<1, 128, 0, stream>>>(bsum, 79);
  k_scan_add<<<79, 256, 0, stream>>>(rowptr, bsum);
  k_fill<<<512, 256, 0, stream>>>(ei, rowptr, deg, srcp);

  // --- layer 1: GAT(3000 -> 512, 3 heads); A = x (f32) fused-converted ---
  k_transpose_tile<<<dim3(C1 / 32, KP1 / 32), 256, 0, stream>>>(W1, w1T, DD, C1, KP1);
  k_gemm8<true, false, true><<<dim3(6, 79), 512, 0, stream>>>(
      (const u16*)x, w1T, h1b, nullptr, NN, C1, KP1, DD, KP1, C1, DD);
  k_attdot1b<<<NN, 192, 0, stream>>>(h1b, asrc1, adst1, as1, ad1, sum1, sq1);
  k_gat1<<<NN, 192, 0, stream>>>(h1b, as1, ad1, rowptr, srcp, b1, g1);
  k_colstats3<<<512, 256, 0, stream>>>(g1, sum1, sq1, (long)NN * HH, HH);
  k_bnrelu4f<<<2048, 256, 0, stream>>>(g1, sum1, sq1, bn1g, bn1b, h2b,
                                       (long)NN * HH / 4, 1.0f / NN);

  // --- layer 2: GAT(512 -> 50, 3 heads) ---
  k_transpose_cvt2<<<256, 256, 0, stream>>>(W2, w2T, HH, C2, 256, HH);
  k_gemm3<false, false><<<dim3(2, 157), 256, 0, stream>>>(h2b, w2T, s2, nullptr,
                                                          NN, C2, HH, HH, C2);
  k_attdot2<<<NN, 64, 0, stream>>>(s2, asrc2, adst2, as2, ad2, sum2, sq2, sum3, sq3);
  k_gat2<<<NN, 64, 0, stream>>>(s2, as2, ad2, rowptr, srcp, b2, zf);
  k_colstats3<<<25, 256, 0, stream>>>(zf, sum2, sq2, (long)NN * ZZ, ZZ);
  k_bnrelu_padf<<<5000, 256, 0, stream>>>(zf, sum2, sq2, bn2g, bn2b, zb);

  // --- decoder ---
  k_cvt_pad4<<<dim3(1, HH), 256, 0, stream>>>(l1w, l1wT, HH, ZZ, 64);      // B^T=[512][64]
  k_gemm3<false, false><<<dim3(4, 157), 256, 0, stream>>>(zb, l1wT, dbuf, l1b,
                                                          NN, HH, 64, 64, HH);
  k_colstats3<<<512, 256, 0, stream>>>(dbuf, sum3, sq3, (long)NN * HH, HH);
  k_bnrelu4f<<<2048, 256, 0, stream>>>(dbuf, sum3, sq3, dbng, dbnb, db,
                                       (long)NN * HH / 4, 1.0f / NN);
  k_cvt_pad4<<<dim3(1, 3072), 256, 0, stream>>>(l2w, l2wT, DD, HH, HH);    // B^T=[3072][512]
  k_gemm8<false, true, false><<<dim3(12, 79), 512, 0, stream>>>(
      db, l2wT, out, l2b, NN, DD, 512, HH, HH, DD, 512);
}

// Round 11
// 716.954 us; speedup vs baseline: 1.1269x; 1.1269x over previous
//
#include <hip/hip_runtime.h>
#include <stdint.h>

typedef unsigned short u16;
typedef __attribute__((ext_vector_type(8))) short s16x8;
typedef __attribute__((ext_vector_type(4))) short s16x4;
typedef __attribute__((ext_vector_type(4))) float f32x4;

#define DEVFN static __device__ __forceinline__

static constexpr int NN = 20000;   // nodes
static constexpr int EE = 160000;  // edges (without self loops)
static constexpr int ET = 180000;  // edges + self loops
static constexpr int DD = 3000;    // input features
static constexpr int HH = 512;     // hidden
static constexpr int ZZ = 50;      // latent
static constexpr int C1 = 1536;    // HEADS*HH
static constexpr int C2 = 150;     // HEADS*ZZ
static constexpr int KA1 = 3008;   // xb row stride (DD padded to x64)
static constexpr int KP1 = 3072;   // GEMM1 K padded to x128; A overreads, B zero

DEVFN u16 f2b(float f) {
  uint32_t u = __builtin_bit_cast(uint32_t, f);
  u += 0x7FFFu + ((u >> 16) & 1u);   // RNE
  return (u16)(u >> 16);
}
DEVFN float b2f(u16 b) {
  uint32_t u = ((uint32_t)b) << 16;
  return __builtin_bit_cast(float, u);
}
DEVFN int edge_at(const void* ei, int mode32, long idx) {
  return mode32 ? ((const int*)ei)[idx] : (int)((const long long*)ei)[idx];
}

// async global->LDS, 16B per lane: lane i lands at (uniform base) + i*16.
typedef __attribute__((address_space(1))) const unsigned int gas_uint;
typedef __attribute__((address_space(3))) unsigned int las_uint;
DEVFN void async16(const u16* g, u16* l) {
  __builtin_amdgcn_global_load_lds((gas_uint*)(uintptr_t)g,
                                   (las_uint*)(unsigned)(uintptr_t)l, 16, 0, 0);
}

// in-block edge_index dtype sniff (int64 => odd 32b words of first 1024 all 0)
DEVFN int sniff_mode(const void* ei, int* nzsh) {
  if (threadIdx.x == 0) *nzsh = 0;
  __syncthreads();
  const int* e32 = (const int*)ei;
  int loc = 0;
  for (int i = threadIdx.x; i < 1024; i += blockDim.x)
    if (e32[2 * i + 1] != 0) loc = 1;
  if (loc) atomicOr(nzsh, 1);
  __syncthreads();
  return *nzsh;   // 1 = int32, 0 = int64
}

// ---------------- CSR build over dst ---------------------------------------
__global__ void k_deg(const void* ei, int* __restrict__ deg) {
  __shared__ int nz;
  int m = sniff_mode(ei, &nz);
  long i = (long)blockIdx.x * blockDim.x + threadIdx.x;
  long st = (long)gridDim.x * blockDim.x;
  for (; i < ET; i += st) {
    int d = (i < EE) ? edge_at(ei, m, EE + i) : (int)(i - EE);
    if ((unsigned)d < (unsigned)NN) atomicAdd(&deg[d], 1);
  }
}

// per-block inclusive scan; also zeroes deg (reused as fill cursor)
__global__ void k_scan_blk(int* __restrict__ deg, int* __restrict__ rowptr,
                           int* __restrict__ bsum) {
  __shared__ int buf[256];
  int b = blockIdx.x, tid = threadIdx.x;
  int i = b * 256 + tid;
  buf[tid] = (i < NN) ? deg[i] : 0;
  if (i < NN) deg[i] = 0;
  __syncthreads();
  for (int off = 1; off < 256; off <<= 1) {
    int t = (tid >= off) ? buf[tid - off] : 0;
    __syncthreads();
    buf[tid] += t;
    __syncthreads();
  }
  if (i < NN) rowptr[i + 1] = buf[tid];
  if (tid == 255) bsum[b] = buf[255];
}
__global__ void k_scan_top(int* __restrict__ bsum, int nb) {
  __shared__ int buf[128];
  int tid = threadIdx.x;
  buf[tid] = (tid < nb) ? bsum[tid] : 0;
  __syncthreads();
  for (int off = 1; off < 128; off <<= 1) {
    int t = (tid >= off) ? buf[tid - off] : 0;
    __syncthreads();
    buf[tid] += t;
    __syncthreads();
  }
  if (tid < nb) bsum[tid] = buf[tid];
}
__global__ void k_scan_add(int* __restrict__ rowptr, const int* __restrict__ bsum) {
  int b = blockIdx.x, tid = threadIdx.x;
  int i = b * 256 + tid;
  if (i == 0) rowptr[0] = 0;
  if (b > 0 && i < NN) rowptr[i + 1] += bsum[b - 1];
}

__global__ void k_fill(const void* ei, const int* __restrict__ rowptr,
                       int* __restrict__ cursor, int* __restrict__ srcp) {
  __shared__ int nz;
  int m = sniff_mode(ei, &nz);
  long i = (long)blockIdx.x * blockDim.x + threadIdx.x;
  long st = (long)gridDim.x * blockDim.x;
  for (; i < ET; i += st) {
    int s, d;
    if (i < EE) { s = edge_at(ei, m, i); d = edge_at(ei, m, EE + i); }
    else { s = d = (int)(i - EE); }
    if ((unsigned)d < (unsigned)NN && (unsigned)s < (unsigned)NN) {
      int pos = atomicAdd(&cursor[d], 1);
      srcp[rowptr[d] + pos] = s;
    }
  }
}

// ---------------- converts -------------------------------------------------
__global__ void k_cvt_pad4(const float* __restrict__ in, u16* __restrict__ out,
                           int R, int Cin, int ldo) {
  int r = blockIdx.y;
  int c = (blockIdx.x * blockDim.x + threadIdx.x) * 4;
  if (c >= ldo) return;
  s16x4 o;
  const float* src = in + (size_t)r * Cin + c;
  if (r < R && c + 4 <= Cin && ((((size_t)r * Cin + c) & 3) == 0)) {
    f32x4 v = *(const f32x4*)src;
#pragma unroll
    for (int j = 0; j < 4; j++) o[j] = (short)f2b(v[j]);
  } else {
#pragma unroll
    for (int j = 0; j < 4; j++)
      o[j] = (short)((r < R && c + j < Cin) ? f2b(src[j]) : (u16)0);
  }
  *(s16x4*)(out + (size_t)r * ldo + c) = o;
}

__global__ void k_transpose_tile(const float* __restrict__ in, u16* __restrict__ out,
                                 int R, int Cc, int ldo) {
  __shared__ float t[32][33];
  int tx = threadIdx.x & 31, ty = threadIdx.x >> 5;   // 32x8
  int c0 = blockIdx.x * 32, r0 = blockIdx.y * 32;
#pragma unroll
  for (int j = 0; j < 4; j++) {
    int r = r0 + ty + j * 8, c = c0 + tx;
    t[ty + j * 8][tx] = (r < R && c < Cc) ? in[(size_t)r * Cc + c] : 0.f;
  }
  __syncthreads();
#pragma unroll
  for (int j = 0; j < 4; j++) {
    int c = c0 + ty + j * 8, r = r0 + tx;
    if (c < Cc && r < ldo) out[(size_t)c * ldo + r] = f2b(t[tx][ty + j * 8]);
  }
}

__global__ void k_transpose_cvt2(const float* __restrict__ in, u16* __restrict__ out,
                                 int R, int C, int Cp, int ldo) {
  long total = (long)Cp * ldo;
  long i = (long)blockIdx.x * blockDim.x + threadIdx.x;
  long st = (long)gridDim.x * blockDim.x;
  for (; i < total; i += st) {
    int c = (int)(i / ldo), r = (int)(i % ldo);
    out[i] = (c < C && r < R) ? f2b(in[(size_t)r * C + c]) : (u16)0;
  }
}

// ============ 8-phase 256x256 bf16 MFMA GEMM (T1..T5, 1-barrier phases) ====
// r8-verified structure: stage slots (t+1)Ah0,(t+1)Ah1,(t+2)Bh0,(t+2)Bh1,
// (t+2)Ah0,(t+2)Ah1,(t+3)Bh0,(t+3)Bh1; vmcnt(4) end ph4/ph8 only; single
// barrier per phase + group-end barrier after VMC4.
template<bool OUT_BF16, bool RELU>
__global__ __launch_bounds__(512, 2) void k_gemm8(
    const u16* __restrict__ Ag, const u16* __restrict__ Bg, void* __restrict__ Cg,
    const float* __restrict__ bias, int M, int Nn, int Kp, int lda, int ldb, int ldc) {
  __shared__ __align__(16) u16 As[2][256][64];   // 64 KB
  __shared__ __align__(16) u16 Bs[2][256][64];   // 64 KB
  int tid = threadIdx.x;
  int lane = tid & 63, wid = tid >> 6;
  int wm = wid >> 2, wn = wid & 3;               // 2 x 4 waves
  int lr = lane & 15, lg = lane >> 4;
  int rx = lr & 7;

  // T1 bijective XCD swizzle
  int nwg = gridDim.x * gridDim.y;
  int wg = blockIdx.y * gridDim.x + blockIdx.x;
  int q = nwg >> 3, r = nwg & 7;
  int xcd = wg & 7, loc = wg >> 3;
  int swz = (xcd < r ? xcd * (q + 1) : r * (q + 1) + (xcd - r) * q) + loc;
  int m0 = (swz / gridDim.x) * 256, n0 = (swz % gridDim.x) * 256;

  int srow = tid >> 3;
  int schunk = ((tid & 7) ^ (srow & 7)) * 8;     // inverse-swizzled source
  const u16* agp[4];
  const u16* bgp[4];
#pragma unroll
  for (int i = 0; i < 4; i++) {
    int ra = i * 64 + srow;
    int ga = m0 + ra; if (ga > M - 1) ga = M - 1;
    agp[i] = Ag + (size_t)ga * lda + schunk;
    bgp[i] = Bg + (size_t)(n0 + ra) * ldb + schunk;
  }
  u16* aB0 = &As[0][0][0]; u16* aB1 = &As[1][0][0];
  u16* bB0 = &Bs[0][0][0]; u16* bB1 = &Bs[1][0][0];

#define SA(cb, h, kt) do {                                                  \
    u16* d_ = ((cb) ? aB1 : aB0);                                           \
    async16(agp[2*(h)]   + (size_t)(kt)*64, d_ + (2*(h))*4096 + wid*512);   \
    async16(agp[2*(h)+1] + (size_t)(kt)*64, d_ + (2*(h)+1)*4096 + wid*512); \
  } while (0)
#define SB(cb, h, kt) do {                                                  \
    u16* d_ = ((cb) ? bB1 : bB0);                                           \
    async16(bgp[2*(h)]   + (size_t)(kt)*64, d_ + (2*(h))*4096 + wid*512);   \
    async16(bgp[2*(h)+1] + (size_t)(kt)*64, d_ + (2*(h)+1)*4096 + wid*512); \
  } while (0)
#define BARX() do { asm volatile("" ::: "memory");                          \
    __builtin_amdgcn_s_barrier(); asm volatile("" ::: "memory"); } while (0)
#define VMC4() asm volatile("s_waitcnt vmcnt(4)" ::: "memory")
#define RDA(dst, cb, mi, ks) dst = *(const s16x8*)&As[cb][wm*128+(mi)*16+lr][(((ks)*4+lg)^rx)*8]
#define RDB(dst, cb, ni, ks) dst = *(const s16x8*)&Bs[cb][wn*64+(ni)*16+lr][(((ks)*4+lg)^rx)*8]

  f32x4 acc[8][4];
#pragma unroll
  for (int mi = 0; mi < 8; mi++)
#pragma unroll
    for (int ni = 0; ni < 4; ni++) {
      acc[mi][ni][0] = 0.f; acc[mi][ni][1] = 0.f;
      acc[mi][ni][2] = 0.f; acc[mi][ni][3] = 0.f;
    }

  s16x8 bfr[2][4];        // B frags: ks x ni (whole group)
  s16x8 f0[4], f1[4];     // A m-pair frags, ping-pong

#define RDB8(cb) do {                                                   \
    RDB(bfr[0][0], cb, 0, 0); RDB(bfr[0][1], cb, 1, 0);                 \
    RDB(bfr[0][2], cb, 2, 0); RDB(bfr[0][3], cb, 3, 0);                 \
    RDB(bfr[1][0], cb, 0, 1); RDB(bfr[1][1], cb, 1, 1);                 \
    RDB(bfr[1][2], cb, 2, 1); RDB(bfr[1][3], cb, 3, 1); } while (0)
#define RDAP(F, cb, P) do {                                             \
    RDA(F[0], cb, 2*(P), 0);   RDA(F[1], cb, 2*(P), 1);                 \
    RDA(F[2], cb, 2*(P)+1, 0); RDA(F[3], cb, 2*(P)+1, 1); } while (0)
#define DO_MFMA(P, F) do {                                              \
    _Pragma("unroll")                                                   \
    for (int ni_ = 0; ni_ < 4; ni_++) {                                 \
      acc[2*(P)][ni_]   = __builtin_amdgcn_mfma_f32_16x16x32_bf16(F[0], bfr[0][ni_], acc[2*(P)][ni_], 0, 0, 0);   \
      acc[2*(P)][ni_]   = __builtin_amdgcn_mfma_f32_16x16x32_bf16(F[1], bfr[1][ni_], acc[2*(P)][ni_], 0, 0, 0);   \
      acc[2*(P)+1][ni_] = __builtin_amdgcn_mfma_f32_16x16x32_bf16(F[2], bfr[0][ni_], acc[2*(P)+1][ni_], 0, 0, 0); \
      acc[2*(P)+1][ni_] = __builtin_amdgcn_mfma_f32_16x16x32_bf16(F[3], bfr[1][ni_], acc[2*(P)+1][ni_], 0, 0, 0); \
    } } while (0)

#define GROUP(cb, S1, S2, S3, S4) do {                                  \
    RDB8(cb); RDAP(f0, cb, 0);                                          \
    S1; BARX();                                                         \
    __builtin_amdgcn_s_setprio(1);                                      \
    RDAP(f1, cb, 1); DO_MFMA(0, f0);                                    \
    __builtin_amdgcn_s_setprio(0);                                      \
    S2; BARX();                                                         \
    __builtin_amdgcn_s_setprio(1);                                      \
    RDAP(f0, cb, 2); DO_MFMA(1, f1);                                    \
    __builtin_amdgcn_s_setprio(0);                                      \
    S3; BARX();                                                         \
    __builtin_amdgcn_s_setprio(1);                                      \
    RDAP(f1, cb, 3); DO_MFMA(2, f0);                                    \
    __builtin_amdgcn_s_setprio(0);                                      \
    S4; BARX();                                                         \
    __builtin_amdgcn_s_setprio(1);                                      \
    DO_MFMA(3, f1);                                                     \
    __builtin_amdgcn_s_setprio(0); VMC4(); BARX();                      \
  } while (0)

  int nt = Kp >> 6;   // even, >= 2
  SB(0, 0, 0); SB(0, 1, 0);
  SA(0, 0, 0); SA(0, 1, 0);
  { int k1 = 1 < nt ? 1 : nt - 1; SB(1, 0, k1); SB(1, 1, k1); }
  VMC4();
  BARX();

  for (int t = 0; t < nt; t += 2) {
    int t2 = (t + 2 < nt) ? t + 2 : nt - 1;
    int t3 = (t + 3 < nt) ? t + 3 : nt - 1;
    GROUP(0, SA(1, 0, t + 1), SA(1, 1, t + 1), SB(0, 0, t2), SB(0, 1, t2));
    GROUP(1, SA(0, 0, t2),    SA(0, 1, t2),    SB(1, 0, t3), SB(1, 1, t3));
  }
  asm volatile("s_waitcnt vmcnt(0)" ::: "memory");

#undef SA
#undef SB
#undef BARX
#undef VMC4
#undef RDA
#undef RDB
#undef RDB8
#undef RDAP
#undef DO_MFMA
#undef GROUP

  // epilogue: D col=lane&15, row=(lane>>4)*4+reg   [m89-verified]
#pragma unroll
  for (int mi = 0; mi < 8; mi++)
#pragma unroll
    for (int ni = 0; ni < 4; ni++) {
      int col = n0 + wn * 64 + ni * 16 + lr;
      if (col >= Nn) continue;
      float bv = bias ? bias[col] : 0.f;
#pragma unroll
      for (int j = 0; j < 4; j++) {
        int row = m0 + wm * 128 + mi * 16 + lg * 4 + j;
        if (row >= M) continue;
        float v = acc[mi][ni][j] + bv;
        if (RELU) v = v > 0.f ? v : 0.f;
        if (OUT_BF16) ((u16*)Cg)[(size_t)row * ldc + col] = f2b(v);
        else          ((float*)Cg)[(size_t)row * ldc + col] = v;
      }
    }
}

// ---------------- 128x128 2-phase GEMM (small shapes: GEMM2, lin1) ---------
template<bool OUT_BF16, bool RELU>
__global__ __launch_bounds__(256) void k_gemm3(
    const u16* __restrict__ Ag, const u16* __restrict__ Bg, void* __restrict__ Cg,
    const float* __restrict__ bias, int M, int Nn, int Kp, int ld, int ldc) {
  __shared__ __align__(16) u16 As[2][128][64];
  __shared__ __align__(16) u16 Bs[2][128][64];
  int tid = threadIdx.x;
  int lane = tid & 63, wid = tid >> 6;
  int wm = wid >> 1, wn = wid & 1;
  int lr = lane & 15, lg = lane >> 4;

  int nwg = gridDim.x * gridDim.y;
  int wg = blockIdx.y * gridDim.x + blockIdx.x;
  int q = nwg >> 3, r = nwg & 7;
  int xcd = wg & 7, loc = wg >> 3;
  int swz = (xcd < r ? xcd * (q + 1) : r * (q + 1) + (xcd - r) * q) + loc;
  int m0 = (swz / gridDim.x) * 128, n0 = (swz % gridDim.x) * 128;

  int srow = lane >> 3;
  int skk = ((lane & 7) ^ srow) * 8;
  const u16* agp[4];
  const u16* bgp[4];
#pragma unroll
  for (int i = 0; i < 4; i++) {
    int ra = wid * 32 + i * 8 + srow;
    int ga = m0 + ra; if (ga > M - 1) ga = M - 1;
    agp[i] = Ag + (size_t)ga * ld + skk;
    bgp[i] = Bg + (size_t)(n0 + ra) * ld + skk;
  }

#define STAGE(bufi, kofs) do {                                   \
    u16* la_ = &As[bufi][0][0] + wid * 2048;                     \
    u16* lb_ = &Bs[bufi][0][0] + wid * 2048;                     \
    _Pragma("unroll")                                            \
    for (int i_ = 0; i_ < 4; i_++) {                             \
      async16(agp[i_] + (kofs), la_ + i_ * 512);                 \
      async16(bgp[i_] + (kofs), lb_ + i_ * 512);                 \
    }                                                            \
  } while (0)

  f32x4 acc[4][4];
#pragma unroll
  for (int mi = 0; mi < 4; mi++)
#pragma unroll
    for (int ni = 0; ni < 4; ni++) {
      acc[mi][ni][0] = 0.f; acc[mi][ni][1] = 0.f; acc[mi][ni][2] = 0.f; acc[mi][ni][3] = 0.f;
    }

  int rx = lr & 7;
  int NT = Kp >> 6;
  STAGE(0, 0);
  for (int t = 0; t < NT; t++) {
    int cur = t & 1;
    if (t + 1 < NT) {
      STAGE(cur ^ 1, (t + 1) * 64);
      asm volatile("s_waitcnt vmcnt(8)" ::: "memory");
    } else {
      asm volatile("s_waitcnt vmcnt(0)" ::: "memory");
    }
    __builtin_amdgcn_s_barrier();
    asm volatile("" ::: "memory");
#pragma unroll
    for (int ks = 0; ks < 2; ks++) {
      int ch = ((ks * 4 + lg) ^ rx) * 8;
      s16x8 a[4], b[4];
#pragma unroll
      for (int mi = 0; mi < 4; mi++)
        a[mi] = *(const s16x8*)&As[cur][wm * 64 + mi * 16 + lr][ch];
#pragma unroll
      for (int ni = 0; ni < 4; ni++)
        b[ni] = *(const s16x8*)&Bs[cur][wn * 64 + ni * 16 + lr][ch];
#pragma unroll
      for (int mi = 0; mi < 4; mi++)
#pragma unroll
        for (int ni = 0; ni < 4; ni++)
          acc[mi][ni] = __builtin_amdgcn_mfma_f32_16x16x32_bf16(a[mi], b[ni], acc[mi][ni], 0, 0, 0);
    }
    asm volatile("" ::: "memory");
    __builtin_amdgcn_s_barrier();
  }
#undef STAGE

#pragma unroll
  for (int mi = 0; mi < 4; mi++)
#pragma unroll
    for (int ni = 0; ni < 4; ni++) {
      int col = n0 + wn * 64 + ni * 16 + lr;
      if (col >= Nn) continue;
      float bv = bias ? bias[col] : 0.f;
#pragma unroll
      for (int j = 0; j < 4; j++) {
        int row = m0 + wm * 64 + mi * 16 + lg * 4 + j;
        if (row >= M) continue;
        float v = acc[mi][ni][j] + bv;
        if (RELU) v = v > 0.f ? v : 0.f;
        if (OUT_BF16) ((u16*)Cg)[(size_t)row * ldc + col] = f2b(v);
        else          ((float*)Cg)[(size_t)row * ldc + col] = v;
      }
    }
}

// ---------------- attention dot products -----------------------------------
__global__ void k_attdot1b(const u16* __restrict__ h1b, const float* __restrict__ asrc,
                           const float* __restrict__ adst, float* __restrict__ as_,
                           float* __restrict__ ad_, float* __restrict__ z0,
                           float* __restrict__ z1) {
  int n = blockIdx.x;
  if (n == 0) {
    for (int i = threadIdx.x; i < HH; i += 192) { z0[i] = 0.f; z1[i] = 0.f; }
  }
  int hd = threadIdx.x >> 6, lane = threadIdx.x & 63;
  s16x8 h = *(const s16x8*)(h1b + (size_t)n * C1 + hd * 512 + lane * 8);
  const float* ap = asrc + hd * 512 + lane * 8;
  const float* dp = adst + hd * 512 + lane * 8;
  f32x4 a0 = *(const f32x4*)ap, a1 = *(const f32x4*)(ap + 4);
  f32x4 d0 = *(const f32x4*)dp, d1 = *(const f32x4*)(dp + 4);
  float ps = 0.f, pd = 0.f;
#pragma unroll
  for (int j = 0; j < 4; j++) {
    float hv = b2f((u16)h[j]);
    ps += hv * a0[j]; pd += hv * d0[j];
    float hw = b2f((u16)h[j + 4]);
    ps += hw * a1[j]; pd += hw * d1[j];
  }
  for (int off = 32; off; off >>= 1) { ps += __shfl_xor(ps, off); pd += __shfl_xor(pd, off); }
  if (lane == 0) { as_[3 * n + hd] = ps; ad_[3 * n + hd] = pd; }
}

__global__ void k_attdot2(const float* __restrict__ s2, const float* __restrict__ asrc,
                          const float* __restrict__ adst, float* __restrict__ as_,
                          float* __restrict__ ad_, float* __restrict__ z0,
                          float* __restrict__ z1, float* __restrict__ z2,
                          float* __restrict__ z3) {
  int n = blockIdx.x, tid = threadIdx.x;
  if (n == 0) {
    for (int i = tid; i < HH; i += 64) { z2[i] = 0.f; z3[i] = 0.f; }
    if (tid < 50) { z0[tid] = 0.f; z1[tid] = 0.f; }
  }
  for (int hd = 0; hd < 3; hd++) {
    float ps = 0.f, pd = 0.f;
    if (tid < 50) {
      float v = s2[(size_t)n * C2 + hd * 50 + tid];
      ps = v * asrc[hd * 50 + tid];
      pd = v * adst[hd * 50 + tid];
    }
    for (int off = 32; off; off >>= 1) { ps += __shfl_xor(ps, off); pd += __shfl_xor(pd, off); }
    if (tid == 0) { as_[3 * n + hd] = ps; ad_[3 * n + hd] = pd; }
  }
}

// ---------------- GAT aggregation ------------------------------------------
// v2: edge scores leaky(as1[s]+ad1[n]) gathered ONCE (max pass) and cached
// in LDS s_ev; sum pass and alpha pass read LDS (gather fallback e>=384).
__global__ __launch_bounds__(192) void k_gat1(
    const u16* __restrict__ h1b, const float* __restrict__ as1,
    const float* __restrict__ ad1, const int* __restrict__ rowptr,
    const int* __restrict__ srcp, const float* __restrict__ bias,
    float* __restrict__ out) {
  int n = blockIdx.x, tid = threadIdx.x;
  __shared__ float sm[3], sden[3];
  __shared__ float s_ev[384][3];
  __shared__ int s_src[128];
  __shared__ float s_alpha[128][3];
  __shared__ float part[3][512];
  int r0 = rowptr[n], deg = rowptr[n + 1] - r0;
  float adl[3] = {ad1[3 * n], ad1[3 * n + 1], ad1[3 * n + 2]};

  if (tid < 64) {
    float mx[3] = {-1e30f, -1e30f, -1e30f};
    for (int e = tid; e < deg; e += 64) {
      int s = srcp[r0 + e];
      float v0 = as1[3 * s] + adl[0];     v0 = v0 > 0.f ? v0 : 0.2f * v0;
      float v1 = as1[3 * s + 1] + adl[1]; v1 = v1 > 0.f ? v1 : 0.2f * v1;
      float v2 = as1[3 * s + 2] + adl[2]; v2 = v2 > 0.f ? v2 : 0.2f * v2;
      if (e < 384) { s_ev[e][0] = v0; s_ev[e][1] = v1; s_ev[e][2] = v2; }
      mx[0] = fmaxf(mx[0], v0); mx[1] = fmaxf(mx[1], v1); mx[2] = fmaxf(mx[2], v2);
    }
#pragma unroll
    for (int hd = 0; hd < 3; hd++)
      for (int off = 32; off; off >>= 1) mx[hd] = fmaxf(mx[hd], __shfl_xor(mx[hd], off));
    float sd[3] = {0.f, 0.f, 0.f};
    for (int e = tid; e < deg; e += 64) {
      float v0, v1, v2;
      if (e < 384) { v0 = s_ev[e][0]; v1 = s_ev[e][1]; v2 = s_ev[e][2]; }
      else {
        int s = srcp[r0 + e];
        v0 = as1[3 * s] + adl[0];     v0 = v0 > 0.f ? v0 : 0.2f * v0;
        v1 = as1[3 * s + 1] + adl[1]; v1 = v1 > 0.f ? v1 : 0.2f * v1;
        v2 = as1[3 * s + 2] + adl[2]; v2 = v2 > 0.f ? v2 : 0.2f * v2;
      }
      sd[0] += __expf(v0 - mx[0]);
      sd[1] += __expf(v1 - mx[1]);
      sd[2] += __expf(v2 - mx[2]);
    }
#pragma unroll
    for (int hd = 0; hd < 3; hd++)
      for (int off = 32; off; off >>= 1) sd[hd] += __shfl_xor(sd[hd], off);
    if (tid == 0) {
#pragma unroll
      for (int hd = 0; hd < 3; hd++) { sm[hd] = mx[hd]; sden[hd] = sd[hd]; }
    }
  }
  __syncthreads();

  int hd = tid >> 6, lane = tid & 63;
  float a[8];
#pragma unroll
  for (int j = 0; j < 8; j++) a[j] = 0.f;

  for (int base = 0; base < deg; base += 128) {
    int cnt = min(128, deg - base);
    if (tid < cnt) {
      int s = srcp[r0 + base + tid];
      s_src[tid] = s;
      float v0, v1, v2;
      if (base + tid < 384) {
        v0 = s_ev[base + tid][0]; v1 = s_ev[base + tid][1]; v2 = s_ev[base + tid][2];
      } else {
        v0 = as1[3 * s] + adl[0];     v0 = v0 > 0.f ? v0 : 0.2f * v0;
        v1 = as1[3 * s + 1] + adl[1]; v1 = v1 > 0.f ? v1 : 0.2f * v1;
        v2 = as1[3 * s + 2] + adl[2]; v2 = v2 > 0.f ? v2 : 0.2f * v2;
      }
      s_alpha[tid][0] = __expf(v0 - sm[0]) / sden[0];
      s_alpha[tid][1] = __expf(v1 - sm[1]) / sden[1];
      s_alpha[tid][2] = __expf(v2 - sm[2]) / sden[2];
    }
    __syncthreads();
    int e = 0;
    for (; e + 2 <= cnt; e += 2) {
      const u16* p0 = h1b + (size_t)s_src[e] * C1 + (hd << 9) + lane * 8;
      const u16* p1 = h1b + (size_t)s_src[e + 1] * C1 + (hd << 9) + lane * 8;
      s16x8 v0 = *(const s16x8*)p0;
      s16x8 v1 = *(const s16x8*)p1;
      float al0 = s_alpha[e][hd], al1 = s_alpha[e + 1][hd];
#pragma unroll
      for (int j = 0; j < 8; j++)
        a[j] += al0 * b2f((u16)v0[j]) + al1 * b2f((u16)v1[j]);
    }
    if (e < cnt) {
      const u16* p0 = h1b + (size_t)s_src[e] * C1 + (hd << 9) + lane * 8;
      s16x8 v0 = *(const s16x8*)p0;
      float al0 = s_alpha[e][hd];
#pragma unroll
      for (int j = 0; j < 8; j++) a[j] += al0 * b2f((u16)v0[j]);
    }
    __syncthreads();
  }

#pragma unroll
  for (int j = 0; j < 8; j++) part[hd][lane * 8 + j] = a[j];
  __syncthreads();
  if (tid < 128) {
    f32x4 p0 = *(const f32x4*)&part[0][tid * 4];
    f32x4 p1 = *(const f32x4*)&part[1][tid * 4];
    f32x4 p2 = *(const f32x4*)&part[2][tid * 4];
    f32x4 bv = *(const f32x4*)(bias + tid * 4);
    f32x4 o;
#pragma unroll
    for (int j = 0; j < 4; j++) o[j] = (p0[j] + p1[j] + p2[j]) * (1.f / 3.f) + bv[j];
    *(f32x4*)(out + (size_t)n * 512 + tid * 4) = o;
  }
}

__global__ void k_gat2(const float* __restrict__ s2, const float* __restrict__ as2,
                       const float* __restrict__ ad2, const int* __restrict__ rowptr,
                       const int* __restrict__ srcp, const float* __restrict__ bias,
                       float* __restrict__ z) {
  int n = blockIdx.x, tid = threadIdx.x;
  __shared__ int s_src[64];
  __shared__ float s_alpha[64][3];
  int r0 = rowptr[n], deg = rowptr[n + 1] - r0;
  float adl[3] = {ad2[3 * n], ad2[3 * n + 1], ad2[3 * n + 2]};

  float mx[3] = {-1e30f, -1e30f, -1e30f};
  for (int e = tid; e < deg; e += 64) {
    int s = srcp[r0 + e];
#pragma unroll
    for (int hd = 0; hd < 3; hd++) {
      float v = as2[3 * s + hd] + adl[hd];
      v = v > 0.f ? v : 0.2f * v;
      mx[hd] = fmaxf(mx[hd], v);
    }
  }
#pragma unroll
  for (int hd = 0; hd < 3; hd++)
    for (int off = 32; off; off >>= 1) mx[hd] = fmaxf(mx[hd], __shfl_xor(mx[hd], off));
  float sd[3] = {0.f, 0.f, 0.f};
  for (int e = tid; e < deg; e += 64) {
    int s = srcp[r0 + e];
#pragma unroll
    for (int hd = 0; hd < 3; hd++) {
      float v = as2[3 * s + hd] + adl[hd];
      v = v > 0.f ? v : 0.2f * v;
      sd[hd] += __expf(v - mx[hd]);
    }
  }
#pragma unroll
  for (int hd = 0; hd < 3; hd++)
    for (int off = 32; off; off >>= 1) sd[hd] += __shfl_xor(sd[hd], off);

  float acc = 0.f;
  for (int base = 0; base < deg; base += 64) {
    int cnt = min(64, deg - base);
    if (tid < cnt) {
      int s = srcp[r0 + base + tid];
      s_src[tid] = s;
#pragma unroll
      for (int hd = 0; hd < 3; hd++) {
        float v = as2[3 * s + hd] + adl[hd];
        v = v > 0.f ? v : 0.2f * v;
        s_alpha[tid][hd] = __expf(v - mx[hd]) / sd[hd];
      }
    }
    __syncthreads();
    if (tid < 50) {
      for (int e = 0; e < cnt; e++) {
        const float* row = s2 + (size_t)s_src[e] * C2;
#pragma unroll
        for (int hd = 0; hd < 3; hd++) acc += s_alpha[e][hd] * row[hd * 50 + tid];
      }
    }
    __syncthreads();
  }
  if (tid < 50) z[(size_t)n * ZZ + tid] = acc * (1.f / 3.f) + bias[tid];
}

// ---------------- BatchNorm (training stats, biased var) -------------------
__global__ void k_colstats3(const float* __restrict__ x, float* __restrict__ gsum,
                            float* __restrict__ gsq, long total, int C) {
  long i = (long)blockIdx.x * blockDim.x + threadIdx.x;
  long st = (long)gridDim.x * blockDim.x;
  int c = (int)(i % C);
  float s = 0.f, q = 0.f;
  for (; i < total; i += st) { float v = x[i]; s += v; q += v * v; }
  atomicAdd(&gsum[c], s);
  atomicAdd(&gsq[c], q);
}

// fused bnfinal+bnrelu for C=512 (scale/shift recomputed from L2-hot sums)
__global__ void k_bnrelu4f(const float* __restrict__ x, const float* __restrict__ gsum,
                           const float* __restrict__ gsq, const float* __restrict__ g,
                           const float* __restrict__ bb, u16* __restrict__ out,
                           long total4, float invN) {
  long i = (long)blockIdx.x * blockDim.x + threadIdx.x;
  long st = (long)gridDim.x * blockDim.x;
  for (; i < total4; i += st) {
    long b = i * 4;
    int c = (int)(b & 511);
    f32x4 v = *(const f32x4*)(x + b);
    f32x4 s = *(const f32x4*)(gsum + c);
    f32x4 qv = *(const f32x4*)(gsq + c);
    f32x4 gg = *(const f32x4*)(g + c);
    f32x4 bv = *(const f32x4*)(bb + c);
    s16x4 o;
#pragma unroll
    for (int j = 0; j < 4; j++) {
      float m = s[j] * invN;
      float var = qv[j] * invN - m * m;
      float sc = gg[j] * rsqrtf(var + 1e-5f);
      float r = (v[j] - m) * sc + bv[j];
      r = r > 0.f ? r : 0.f;
      o[j] = (short)f2b(r);
    }
    *(s16x4*)(out + b) = o;
  }
}

// fused bnfinal + bnrelu + pad for the 50->64 latent (zb)
__global__ void k_bnrelu_padf(const float* __restrict__ x, const float* __restrict__ gsum,
                              const float* __restrict__ gsq, const float* __restrict__ g,
                              const float* __restrict__ bb, u16* __restrict__ out) {
  int i = blockIdx.x * blockDim.x + threadIdx.x;
  if (i >= NN * 64) return;
  int c = i & 63, r = i >> 6;
  float v = 0.f;
  if (c < 50) {
    float m = gsum[c] * (1.0f / NN);
    float var = gsq[c] * (1.0f / NN) - m * m;
    float sc = g[c] * rsqrtf(var + 1e-5f);
    v = (x[r * 50 + c] - m) * sc + bb[c];
    v = v > 0.f ? v : 0.f;
  }
  out[i] = f2b(v);
}

// ---------------------------------------------------------------------------
extern "C" void kernel_launch(void* const* d_in, const int* in_sizes, int n_in,
                              void* d_out, int out_size, void* d_ws, size_t ws_size,
                              hipStream_t stream) {
  (void)in_sizes; (void)n_in; (void)out_size;
  const float* x     = (const float*)d_in[0];
  const void*  ei    = d_in[1];
  const float* W1    = (const float*)d_in[2];
  const float* asrc1 = (const float*)d_in[3];
  const float* adst1 = (const float*)d_in[4];
  const float* b1    = (const float*)d_in[5];
  const float* bn1g  = (const float*)d_in[6];
  const float* bn1b  = (const float*)d_in[7];
  const float* W2    = (const float*)d_in[8];
  const float* asrc2 = (const float*)d_in[9];
  const float* adst2 = (const float*)d_in[10];
  const float* b2    = (const float*)d_in[11];
  const float* bn2g  = (const float*)d_in[12];
  const float* bn2b  = (const float*)d_in[13];
  const float* l1w   = (const float*)d_in[14];
  const float* l1b   = (const float*)d_in[15];
  const float* dbng  = (const float*)d_in[16];
  const float* dbnb  = (const float*)d_in[17];
  const float* l2w   = (const float*)d_in[18];
  const float* l2b   = (const float*)d_in[19];
  float* out = (float*)d_out;
  char* ws = (char*)d_ws;

  size_t off = 0;
  auto alloc = [&](size_t b) { size_t r = off; off += (b + 255) & ~(size_t)255; return r; };
  const size_t oXB  = alloc(120320000);                  // xb [20000][3008]; reused below
  const size_t oH1  = alloc(61440000);                   // h1b [20000][1536]; later db
  const size_t oW1T = alloc((size_t)C1 * KP1 * 2);       // w1T [1536][3072]
  const size_t oAS1 = alloc((size_t)NN * 12), oAD1 = alloc((size_t)NN * 12);
  const size_t oAS2 = alloc((size_t)NN * 12), oAD2 = alloc((size_t)NN * 12);
  const size_t oRP  = alloc((size_t)(NN + 1) * 4);
  const size_t oDEG = alloc((size_t)NN * 4);
  const size_t oSRC = alloc((size_t)ET * 4);
  const size_t oBSUM = alloc(512);
  const size_t oS1 = alloc(2048), oQ1 = alloc(2048);
  const size_t oS2 = alloc(2048), oQ2 = alloc(2048);
  const size_t oS3 = alloc(2048), oQ3 = alloc(2048);
  if (ws_size < off) return;

  u16*   xb   = (u16*)(ws + oXB);                        // [20000][3008]
  float* g1   = (float*)(ws + oXB);
  u16*   h2b  = (u16*)(ws + oXB + 40960000);
  float* s2   = (float*)(ws + oXB + 61440000);
  float* zf   = (float*)(ws + oXB + 73440000);
  u16*   zb   = (u16*)(ws + oXB + 77440000);
  u16*   w2T  = (u16*)(ws + oXB + 80000000);
  u16*   l1wT = (u16*)(ws + oXB + 80262400);
  u16*   l2wT = (u16*)(ws + oXB + 80328192);
  float* dbuf = (float*)(ws + oXB);
  u16*   h1b  = (u16*)(ws + oH1);
  u16*   db   = (u16*)(ws + oH1);
  u16*   w1T  = (u16*)(ws + oW1T);
  int* bsum   = (int*)(ws + oBSUM);
  int* deg    = (int*)(ws + oDEG);
  int* rowptr = (int*)(ws + oRP);
  int* srcp   = (int*)(ws + oSRC);
  float *as1 = (float*)(ws + oAS1), *ad1 = (float*)(ws + oAD1);
  float *as2 = (float*)(ws + oAS2), *ad2 = (float*)(ws + oAD2);
  float *sum1 = (float*)(ws + oS1), *sq1 = (float*)(ws + oQ1);
  float *sum2 = (float*)(ws + oS2), *sq2 = (float*)(ws + oQ2);
  float *sum3 = (float*)(ws + oS3), *sq3 = (float*)(ws + oQ3);

  // --- CSR by dst (with self loops) ---
  hipMemsetAsync(deg, 0, (size_t)NN * 4, stream);
  k_deg<<<512, 256, 0, stream>>>(ei, deg);
  k_scan_blk<<<79, 256, 0, stream>>>(deg, rowptr, bsum);   // also zeroes deg
  k_scan_top<<<1, 128, 0, stream>>>(bsum, 79);
  k_scan_add<<<79, 256, 0, stream>>>(rowptr, bsum);
  k_fill<<<512, 256, 0, stream>>>(ei, rowptr, deg, srcp);

  // --- layer 1: GAT(3000 -> 512, 3 heads) ---
  k_cvt_pad4<<<dim3(3, NN), 256, 0, stream>>>(x, xb, NN, DD, KA1);
  k_transpose_tile<<<dim3(C1 / 32, KP1 / 32), 256, 0, stream>>>(W1, w1T, DD, C1, KP1);
  k_gemm8<true, false><<<dim3(6, 79), 512, 0, stream>>>(xb, w1T, h1b, nullptr,
                                                        NN, C1, KP1, KA1, KP1, C1);
  k_attdot1b<<<NN, 192, 0, stream>>>(h1b, asrc1, adst1, as1, ad1, sum1, sq1);
  k_gat1<<<NN, 192, 0, stream>>>(h1b, as1, ad1, rowptr, srcp, b1, g1);
  k_colstats3<<<512, 256, 0, stream>>>(g1, sum1, sq1, (long)NN * HH, HH);
  k_bnrelu4f<<<2048, 256, 0, stream>>>(g1, sum1, sq1, bn1g, bn1b, h2b,
                                       (long)NN * HH / 4, 1.0f / NN);

  // --- layer 2: GAT(512 -> 50, 3 heads) ---
  k_transpose_cvt2<<<256, 256, 0, stream>>>(W2, w2T, HH, C2, 256, HH);
  k_gemm3<false, false><<<dim3(2, 157), 256, 0, stream>>>(h2b, w2T, s2, nullptr,
                                                          NN, C2, HH, HH, C2);
  k_attdot2<<<NN, 64, 0, stream>>>(s2, asrc2, adst2, as2, ad2, sum2, sq2, sum3, sq3);
  k_gat2<<<NN, 64, 0, stream>>>(s2, as2, ad2, rowptr, srcp, b2, zf);
  k_colstats3<<<25, 256, 0, stream>>>(zf, sum2, sq2, (long)NN * ZZ, ZZ);
  k_bnrelu_padf<<<5000, 256, 0, stream>>>(zf, sum2, sq2, bn2g, bn2b, zb);

  // --- decoder ---
  k_cvt_pad4<<<dim3(1, HH), 256, 0, stream>>>(l1w, l1wT, HH, ZZ, 64);      // B^T=[512][64]
  k_gemm3<false, false><<<dim3(4, 157), 256, 0, stream>>>(zb, l1wT, dbuf, l1b,
                                                          NN, HH, 64, 64, HH);
  k_colstats3<<<512, 256, 0, stream>>>(dbuf, sum3, sq3, (long)NN * HH, HH);
  k_bnrelu4f<<<2048, 256, 0, stream>>>(dbuf, sum3, sq3, dbng, dbnb, db,
                                       (long)NN * HH / 4, 1.0f / NN);
  k_cvt_pad4<<<dim3(1, 3072), 256, 0, stream>>>(l2w, l2wT, DD, HH, HH);    // B^T=[3072][512]
  k_gemm8<false, true><<<dim3(12, 79), 512, 0, stream>>>(db, l2wT, out, l2b,
                                                         NN, DD, 512, HH, HH, DD);
}

// Round 12
// 714.977 us; speedup vs baseline: 1.1300x; 1.0028x over previous
//
#include <hip/hip_runtime.h>
#include <stdint.h>

typedef unsigned short u16;
typedef __attribute__((ext_vector_type(8))) short s16x8;
typedef __attribute__((ext_vector_type(4))) short s16x4;
typedef __attribute__((ext_vector_type(4))) float f32x4;

#define DEVFN static __device__ __forceinline__

static constexpr int NN = 20000;   // nodes
static constexpr int EE = 160000;  // edges (without self loops)
static constexpr int ET = 180000;  // edges + self loops
static constexpr int DD = 3000;    // input features
static constexpr int HH = 512;     // hidden
static constexpr int ZZ = 50;      // latent
static constexpr int C1 = 1536;    // HEADS*HH
static constexpr int C2 = 150;     // HEADS*ZZ
static constexpr int KA1 = 3008;   // xb row stride (DD padded to x64)
static constexpr int KP1 = 3072;   // GEMM1 K padded to x128; A overreads, B zero

DEVFN u16 f2b(float f) {
  uint32_t u = __builtin_bit_cast(uint32_t, f);
  u += 0x7FFFu + ((u >> 16) & 1u);   // RNE
  return (u16)(u >> 16);
}
DEVFN float b2f(u16 b) {
  uint32_t u = ((uint32_t)b) << 16;
  return __builtin_bit_cast(float, u);
}
DEVFN int edge_at(const void* ei, int mode32, long idx) {
  return mode32 ? ((const int*)ei)[idx] : (int)((const long long*)ei)[idx];
}

// async global->LDS, 16B per lane: lane i lands at (uniform base) + i*16.
typedef __attribute__((address_space(1))) const unsigned int gas_uint;
typedef __attribute__((address_space(3))) unsigned int las_uint;
DEVFN void async16(const u16* g, u16* l) {
  __builtin_amdgcn_global_load_lds((gas_uint*)(uintptr_t)g,
                                   (las_uint*)(unsigned)(uintptr_t)l, 16, 0, 0);
}

// in-block edge_index dtype sniff (int64 => odd 32b words of first 1024 all 0)
DEVFN int sniff_mode(const void* ei, int* nzsh) {
  if (threadIdx.x == 0) *nzsh = 0;
  __syncthreads();
  const int* e32 = (const int*)ei;
  int loc = 0;
  for (int i = threadIdx.x; i < 1024; i += blockDim.x)
    if (e32[2 * i + 1] != 0) loc = 1;
  if (loc) atomicOr(nzsh, 1);
  __syncthreads();
  return *nzsh;   // 1 = int32, 0 = int64
}

// ---------------- CSR build over dst ---------------------------------------
__global__ void k_deg(const void* ei, int* __restrict__ deg) {
  __shared__ int nz;
  int m = sniff_mode(ei, &nz);
  long i = (long)blockIdx.x * blockDim.x + threadIdx.x;
  long st = (long)gridDim.x * blockDim.x;
  for (; i < ET; i += st) {
    int d = (i < EE) ? edge_at(ei, m, EE + i) : (int)(i - EE);
    if ((unsigned)d < (unsigned)NN) atomicAdd(&deg[d], 1);
  }
}

// per-block inclusive scan; also zeroes deg (reused as fill cursor)
__global__ void k_scan_blk(int* __restrict__ deg, int* __restrict__ rowptr,
                           int* __restrict__ bsum) {
  __shared__ int buf[256];
  int b = blockIdx.x, tid = threadIdx.x;
  int i = b * 256 + tid;
  buf[tid] = (i < NN) ? deg[i] : 0;
  if (i < NN) deg[i] = 0;
  __syncthreads();
  for (int off = 1; off < 256; off <<= 1) {
    int t = (tid >= off) ? buf[tid - off] : 0;
    __syncthreads();
    buf[tid] += t;
    __syncthreads();
  }
  if (i < NN) rowptr[i + 1] = buf[tid];
  if (tid == 255) bsum[b] = buf[255];
}
__global__ void k_scan_top(int* __restrict__ bsum, int nb) {
  __shared__ int buf[128];
  int tid = threadIdx.x;
  buf[tid] = (tid < nb) ? bsum[tid] : 0;
  __syncthreads();
  for (int off = 1; off < 128; off <<= 1) {
    int t = (tid >= off) ? buf[tid - off] : 0;
    __syncthreads();
    buf[tid] += t;
    __syncthreads();
  }
  if (tid < nb) bsum[tid] = buf[tid];
}
__global__ void k_scan_add(int* __restrict__ rowptr, const int* __restrict__ bsum) {
  int b = blockIdx.x, tid = threadIdx.x;
  int i = b * 256 + tid;
  if (i == 0) rowptr[0] = 0;
  if (b > 0 && i < NN) rowptr[i + 1] += bsum[b - 1];
}

__global__ void k_fill(const void* ei, const int* __restrict__ rowptr,
                       int* __restrict__ cursor, int* __restrict__ srcp) {
  __shared__ int nz;
  int m = sniff_mode(ei, &nz);
  long i = (long)blockIdx.x * blockDim.x + threadIdx.x;
  long st = (long)gridDim.x * blockDim.x;
  for (; i < ET; i += st) {
    int s, d;
    if (i < EE) { s = edge_at(ei, m, i); d = edge_at(ei, m, EE + i); }
    else { s = d = (int)(i - EE); }
    if ((unsigned)d < (unsigned)NN && (unsigned)s < (unsigned)NN) {
      int pos = atomicAdd(&cursor[d], 1);
      srcp[rowptr[d] + pos] = s;
    }
  }
}

// ---------------- converts -------------------------------------------------
__global__ void k_cvt_pad4(const float* __restrict__ in, u16* __restrict__ out,
                           int R, int Cin, int ldo) {
  int r = blockIdx.y;
  int c = (blockIdx.x * blockDim.x + threadIdx.x) * 4;
  if (c >= ldo) return;
  s16x4 o;
  const float* src = in + (size_t)r * Cin + c;
  if (r < R && c + 4 <= Cin && ((((size_t)r * Cin + c) & 3) == 0)) {
    f32x4 v = *(const f32x4*)src;
#pragma unroll
    for (int j = 0; j < 4; j++) o[j] = (short)f2b(v[j]);
  } else {
#pragma unroll
    for (int j = 0; j < 4; j++)
      o[j] = (short)((r < R && c + j < Cin) ? f2b(src[j]) : (u16)0);
  }
  *(s16x4*)(out + (size_t)r * ldo + c) = o;
}

__global__ void k_transpose_tile(const float* __restrict__ in, u16* __restrict__ out,
                                 int R, int Cc, int ldo) {
  __shared__ float t[32][33];
  int tx = threadIdx.x & 31, ty = threadIdx.x >> 5;   // 32x8
  int c0 = blockIdx.x * 32, r0 = blockIdx.y * 32;
#pragma unroll
  for (int j = 0; j < 4; j++) {
    int r = r0 + ty + j * 8, c = c0 + tx;
    t[ty + j * 8][tx] = (r < R && c < Cc) ? in[(size_t)r * Cc + c] : 0.f;
  }
  __syncthreads();
#pragma unroll
  for (int j = 0; j < 4; j++) {
    int c = c0 + ty + j * 8, r = r0 + tx;
    if (c < Cc && r < ldo) out[(size_t)c * ldo + r] = f2b(t[tx][ty + j * 8]);
  }
}

__global__ void k_transpose_cvt2(const float* __restrict__ in, u16* __restrict__ out,
                                 int R, int C, int Cp, int ldo) {
  long total = (long)Cp * ldo;
  long i = (long)blockIdx.x * blockDim.x + threadIdx.x;
  long st = (long)gridDim.x * blockDim.x;
  for (; i < total; i += st) {
    int c = (int)(i / ldo), r = (int)(i % ldo);
    out[i] = (c < C && r < R) ? f2b(in[(size_t)r * C + c]) : (u16)0;
  }
}

// ============ 8-phase 256x256 bf16 MFMA GEMM (T1..T5, 1-barrier phases) ====
// r8-verified structure (do not touch): stage slots (t+1)Ah0,(t+1)Ah1,
// (t+2)Bh0,(t+2)Bh1,(t+2)Ah0,(t+2)Ah1,(t+3)Bh0,(t+3)Bh1; vmcnt(4) end
// ph4/ph8 only; single barrier per phase + group-end barrier after VMC4.
template<bool OUT_BF16, bool RELU>
__global__ __launch_bounds__(512, 2) void k_gemm8(
    const u16* __restrict__ Ag, const u16* __restrict__ Bg, void* __restrict__ Cg,
    const float* __restrict__ bias, int M, int Nn, int Kp, int lda, int ldb, int ldc) {
  __shared__ __align__(16) u16 As[2][256][64];   // 64 KB
  __shared__ __align__(16) u16 Bs[2][256][64];   // 64 KB
  int tid = threadIdx.x;
  int lane = tid & 63, wid = tid >> 6;
  int wm = wid >> 2, wn = wid & 3;               // 2 x 4 waves
  int lr = lane & 15, lg = lane >> 4;
  int rx = lr & 7;

  // T1 bijective XCD swizzle
  int nwg = gridDim.x * gridDim.y;
  int wg = blockIdx.y * gridDim.x + blockIdx.x;
  int q = nwg >> 3, r = nwg & 7;
  int xcd = wg & 7, loc = wg >> 3;
  int swz = (xcd < r ? xcd * (q + 1) : r * (q + 1) + (xcd - r) * q) + loc;
  int m0 = (swz / gridDim.x) * 256, n0 = (swz % gridDim.x) * 256;

  int srow = tid >> 3;
  int schunk = ((tid & 7) ^ (srow & 7)) * 8;     // inverse-swizzled source
  const u16* agp[4];
  const u16* bgp[4];
#pragma unroll
  for (int i = 0; i < 4; i++) {
    int ra = i * 64 + srow;
    int ga = m0 + ra; if (ga > M - 1) ga = M - 1;
    agp[i] = Ag + (size_t)ga * lda + schunk;
    bgp[i] = Bg + (size_t)(n0 + ra) * ldb + schunk;
  }
  u16* aB0 = &As[0][0][0]; u16* aB1 = &As[1][0][0];
  u16* bB0 = &Bs[0][0][0]; u16* bB1 = &Bs[1][0][0];

#define SA(cb, h, kt) do {                                                  \
    u16* d_ = ((cb) ? aB1 : aB0);                                           \
    async16(agp[2*(h)]   + (size_t)(kt)*64, d_ + (2*(h))*4096 + wid*512);   \
    async16(agp[2*(h)+1] + (size_t)(kt)*64, d_ + (2*(h)+1)*4096 + wid*512); \
  } while (0)
#define SB(cb, h, kt) do {                                                  \
    u16* d_ = ((cb) ? bB1 : bB0);                                           \
    async16(bgp[2*(h)]   + (size_t)(kt)*64, d_ + (2*(h))*4096 + wid*512);   \
    async16(bgp[2*(h)+1] + (size_t)(kt)*64, d_ + (2*(h)+1)*4096 + wid*512); \
  } while (0)
#define BARX() do { asm volatile("" ::: "memory");                          \
    __builtin_amdgcn_s_barrier(); asm volatile("" ::: "memory"); } while (0)
#define VMC4() asm volatile("s_waitcnt vmcnt(4)" ::: "memory")
#define RDA(dst, cb, mi, ks) dst = *(const s16x8*)&As[cb][wm*128+(mi)*16+lr][(((ks)*4+lg)^rx)*8]
#define RDB(dst, cb, ni, ks) dst = *(const s16x8*)&Bs[cb][wn*64+(ni)*16+lr][(((ks)*4+lg)^rx)*8]

  f32x4 acc[8][4];
#pragma unroll
  for (int mi = 0; mi < 8; mi++)
#pragma unroll
    for (int ni = 0; ni < 4; ni++) {
      acc[mi][ni][0] = 0.f; acc[mi][ni][1] = 0.f;
      acc[mi][ni][2] = 0.f; acc[mi][ni][3] = 0.f;
    }

  s16x8 bfr[2][4];        // B frags: ks x ni (whole group)
  s16x8 f0[4], f1[4];     // A m-pair frags, ping-pong

#define RDB8(cb) do {                                                   \
    RDB(bfr[0][0], cb, 0, 0); RDB(bfr[0][1], cb, 1, 0);                 \
    RDB(bfr[0][2], cb, 2, 0); RDB(bfr[0][3], cb, 3, 0);                 \
    RDB(bfr[1][0], cb, 0, 1); RDB(bfr[1][1], cb, 1, 1);                 \
    RDB(bfr[1][2], cb, 2, 1); RDB(bfr[1][3], cb, 3, 1); } while (0)
#define RDAP(F, cb, P) do {                                             \
    RDA(F[0], cb, 2*(P), 0);   RDA(F[1], cb, 2*(P), 1);                 \
    RDA(F[2], cb, 2*(P)+1, 0); RDA(F[3], cb, 2*(P)+1, 1); } while (0)
#define DO_MFMA(P, F) do {                                              \
    _Pragma("unroll")                                                   \
    for (int ni_ = 0; ni_ < 4; ni_++) {                                 \
      acc[2*(P)][ni_]   = __builtin_amdgcn_mfma_f32_16x16x32_bf16(F[0], bfr[0][ni_], acc[2*(P)][ni_], 0, 0, 0);   \
      acc[2*(P)][ni_]   = __builtin_amdgcn_mfma_f32_16x16x32_bf16(F[1], bfr[1][ni_], acc[2*(P)][ni_], 0, 0, 0);   \
      acc[2*(P)+1][ni_] = __builtin_amdgcn_mfma_f32_16x16x32_bf16(F[2], bfr[0][ni_], acc[2*(P)+1][ni_], 0, 0, 0); \
      acc[2*(P)+1][ni_] = __builtin_amdgcn_mfma_f32_16x16x32_bf16(F[3], bfr[1][ni_], acc[2*(P)+1][ni_], 0, 0, 0); \
    } } while (0)

#define GROUP(cb, S1, S2, S3, S4) do {                                  \
    RDB8(cb); RDAP(f0, cb, 0);                                          \
    S1; BARX();                                                         \
    __builtin_amdgcn_s_setprio(1);                                      \
    RDAP(f1, cb, 1); DO_MFMA(0, f0);                                    \
    __builtin_amdgcn_s_setprio(0);                                      \
    S2; BARX();                                                         \
    __builtin_amdgcn_s_setprio(1);                                      \
    RDAP(f0, cb, 2); DO_MFMA(1, f1);                                    \
    __builtin_amdgcn_s_setprio(0);                                      \
    S3; BARX();                                                         \
    __builtin_amdgcn_s_setprio(1);                                      \
    RDAP(f1, cb, 3); DO_MFMA(2, f0);                                    \
    __builtin_amdgcn_s_setprio(0);                                      \
    S4; BARX();                                                         \
    __builtin_amdgcn_s_setprio(1);                                      \
    DO_MFMA(3, f1);                                                     \
    __builtin_amdgcn_s_setprio(0); VMC4(); BARX();                      \
  } while (0)

  int nt = Kp >> 6;   // even, >= 2
  SB(0, 0, 0); SB(0, 1, 0);
  SA(0, 0, 0); SA(0, 1, 0);
  { int k1 = 1 < nt ? 1 : nt - 1; SB(1, 0, k1); SB(1, 1, k1); }
  VMC4();
  BARX();

  for (int t = 0; t < nt; t += 2) {
    int t2 = (t + 2 < nt) ? t + 2 : nt - 1;
    int t3 = (t + 3 < nt) ? t + 3 : nt - 1;
    GROUP(0, SA(1, 0, t + 1), SA(1, 1, t + 1), SB(0, 0, t2), SB(0, 1, t2));
    GROUP(1, SA(0, 0, t2),    SA(0, 1, t2),    SB(1, 0, t3), SB(1, 1, t3));
  }
  asm volatile("s_waitcnt vmcnt(0)" ::: "memory");

#undef SA
#undef SB
#undef BARX
#undef VMC4
#undef RDA
#undef RDB
#undef RDB8
#undef RDAP
#undef DO_MFMA
#undef GROUP

  // epilogue: D col=lane&15, row=(lane>>4)*4+reg   [m89-verified]
#pragma unroll
  for (int mi = 0; mi < 8; mi++)
#pragma unroll
    for (int ni = 0; ni < 4; ni++) {
      int col = n0 + wn * 64 + ni * 16 + lr;
      if (col >= Nn) continue;
      float bv = bias ? bias[col] : 0.f;
#pragma unroll
      for (int j = 0; j < 4; j++) {
        int row = m0 + wm * 128 + mi * 16 + lg * 4 + j;
        if (row >= M) continue;
        float v = acc[mi][ni][j] + bv;
        if (RELU) v = v > 0.f ? v : 0.f;
        if (OUT_BF16) ((u16*)Cg)[(size_t)row * ldc + col] = f2b(v);
        else          ((float*)Cg)[(size_t)row * ldc + col] = v;
      }
    }
}

// ---------------- 128x128 2-phase GEMM (small shapes: GEMM2, lin1) ---------
template<bool OUT_BF16, bool RELU>
__global__ __launch_bounds__(256) void k_gemm3(
    const u16* __restrict__ Ag, const u16* __restrict__ Bg, void* __restrict__ Cg,
    const float* __restrict__ bias, int M, int Nn, int Kp, int ld, int ldc) {
  __shared__ __align__(16) u16 As[2][128][64];
  __shared__ __align__(16) u16 Bs[2][128][64];
  int tid = threadIdx.x;
  int lane = tid & 63, wid = tid >> 6;
  int wm = wid >> 1, wn = wid & 1;
  int lr = lane & 15, lg = lane >> 4;

  int nwg = gridDim.x * gridDim.y;
  int wg = blockIdx.y * gridDim.x + blockIdx.x;
  int q = nwg >> 3, r = nwg & 7;
  int xcd = wg & 7, loc = wg >> 3;
  int swz = (xcd < r ? xcd * (q + 1) : r * (q + 1) + (xcd - r) * q) + loc;
  int m0 = (swz / gridDim.x) * 128, n0 = (swz % gridDim.x) * 128;

  int srow = lane >> 3;
  int skk = ((lane & 7) ^ srow) * 8;
  const u16* agp[4];
  const u16* bgp[4];
#pragma unroll
  for (int i = 0; i < 4; i++) {
    int ra = wid * 32 + i * 8 + srow;
    int ga = m0 + ra; if (ga > M - 1) ga = M - 1;
    agp[i] = Ag + (size_t)ga * ld + skk;
    bgp[i] = Bg + (size_t)(n0 + ra) * ld + skk;
  }

#define STAGE(bufi, kofs) do {                                   \
    u16* la_ = &As[bufi][0][0] + wid * 2048;                     \
    u16* lb_ = &Bs[bufi][0][0] + wid * 2048;                     \
    _Pragma("unroll")                                            \
    for (int i_ = 0; i_ < 4; i_++) {                             \
      async16(agp[i_] + (kofs), la_ + i_ * 512);                 \
      async16(bgp[i_] + (kofs), lb_ + i_ * 512);                 \
    }                                                            \
  } while (0)

  f32x4 acc[4][4];
#pragma unroll
  for (int mi = 0; mi < 4; mi++)
#pragma unroll
    for (int ni = 0; ni < 4; ni++) {
      acc[mi][ni][0] = 0.f; acc[mi][ni][1] = 0.f; acc[mi][ni][2] = 0.f; acc[mi][ni][3] = 0.f;
    }

  int rx = lr & 7;
  int NT = Kp >> 6;
  STAGE(0, 0);
  for (int t = 0; t < NT; t++) {
    int cur = t & 1;
    if (t + 1 < NT) {
      STAGE(cur ^ 1, (t + 1) * 64);
      asm volatile("s_waitcnt vmcnt(8)" ::: "memory");
    } else {
      asm volatile("s_waitcnt vmcnt(0)" ::: "memory");
    }
    __builtin_amdgcn_s_barrier();
    asm volatile("" ::: "memory");
#pragma unroll
    for (int ks = 0; ks < 2; ks++) {
      int ch = ((ks * 4 + lg) ^ rx) * 8;
      s16x8 a[4], b[4];
#pragma unroll
      for (int mi = 0; mi < 4; mi++)
        a[mi] = *(const s16x8*)&As[cur][wm * 64 + mi * 16 + lr][ch];
#pragma unroll
      for (int ni = 0; ni < 4; ni++)
        b[ni] = *(const s16x8*)&Bs[cur][wn * 64 + ni * 16 + lr][ch];
#pragma unroll
      for (int mi = 0; mi < 4; mi++)
#pragma unroll
        for (int ni = 0; ni < 4; ni++)
          acc[mi][ni] = __builtin_amdgcn_mfma_f32_16x16x32_bf16(a[mi], b[ni], acc[mi][ni], 0, 0, 0);
    }
    asm volatile("" ::: "memory");
    __builtin_amdgcn_s_barrier();
  }
#undef STAGE

#pragma unroll
  for (int mi = 0; mi < 4; mi++)
#pragma unroll
    for (int ni = 0; ni < 4; ni++) {
      int col = n0 + wn * 64 + ni * 16 + lr;
      if (col >= Nn) continue;
      float bv = bias ? bias[col] : 0.f;
#pragma unroll
      for (int j = 0; j < 4; j++) {
        int row = m0 + wm * 64 + mi * 16 + lg * 4 + j;
        if (row >= M) continue;
        float v = acc[mi][ni][j] + bv;
        if (RELU) v = v > 0.f ? v : 0.f;
        if (OUT_BF16) ((u16*)Cg)[(size_t)row * ldc + col] = f2b(v);
        else          ((float*)Cg)[(size_t)row * ldc + col] = v;
      }
    }
}

// ---------------- attention dot products -----------------------------------
__global__ void k_attdot1b(const u16* __restrict__ h1b, const float* __restrict__ asrc,
                           const float* __restrict__ adst, float* __restrict__ as_,
                           float* __restrict__ ad_, float* __restrict__ z0,
                           float* __restrict__ z1) {
  int n = blockIdx.x;
  if (n == 0) {
    for (int i = threadIdx.x; i < HH; i += 192) { z0[i] = 0.f; z1[i] = 0.f; }
  }
  int hd = threadIdx.x >> 6, lane = threadIdx.x & 63;
  s16x8 h = *(const s16x8*)(h1b + (size_t)n * C1 + hd * 512 + lane * 8);
  const float* ap = asrc + hd * 512 + lane * 8;
  const float* dp = adst + hd * 512 + lane * 8;
  f32x4 a0 = *(const f32x4*)ap, a1 = *(const f32x4*)(ap + 4);
  f32x4 d0 = *(const f32x4*)dp, d1 = *(const f32x4*)(dp + 4);
  float ps = 0.f, pd = 0.f;
#pragma unroll
  for (int j = 0; j < 4; j++) {
    float hv = b2f((u16)h[j]);
    ps += hv * a0[j]; pd += hv * d0[j];
    float hw = b2f((u16)h[j + 4]);
    ps += hw * a1[j]; pd += hw * d1[j];
  }
  for (int off = 32; off; off >>= 1) { ps += __shfl_xor(ps, off); pd += __shfl_xor(pd, off); }
  if (lane == 0) { as_[3 * n + hd] = ps; ad_[3 * n + hd] = pd; }
}

__global__ void k_attdot2(const float* __restrict__ s2, const float* __restrict__ asrc,
                          const float* __restrict__ adst, float* __restrict__ as_,
                          float* __restrict__ ad_, float* __restrict__ z0,
                          float* __restrict__ z1, float* __restrict__ z2,
                          float* __restrict__ z3) {
  int n = blockIdx.x, tid = threadIdx.x;
  if (n == 0) {
    for (int i = tid; i < HH; i += 64) { z2[i] = 0.f; z3[i] = 0.f; }
    if (tid < 50) { z0[tid] = 0.f; z1[tid] = 0.f; }
  }
  for (int hd = 0; hd < 3; hd++) {
    float ps = 0.f, pd = 0.f;
    if (tid < 50) {
      float v = s2[(size_t)n * C2 + hd * 50 + tid];
      ps = v * asrc[hd * 50 + tid];
      pd = v * adst[hd * 50 + tid];
    }
    for (int off = 32; off; off >>= 1) { ps += __shfl_xor(ps, off); pd += __shfl_xor(pd, off); }
    if (tid == 0) { as_[3 * n + hd] = ps; ad_[3 * n + hd] = pd; }
  }
}

// ---------------- GAT aggregation ------------------------------------------
// scores gathered once (max pass) and LDS-cached; aggregation 4-edge unroll.
__global__ __launch_bounds__(192) void k_gat1(
    const u16* __restrict__ h1b, const float* __restrict__ as1,
    const float* __restrict__ ad1, const int* __restrict__ rowptr,
    const int* __restrict__ srcp, const float* __restrict__ bias,
    float* __restrict__ out) {
  int n = blockIdx.x, tid = threadIdx.x;
  __shared__ float sm[3], sden[3];
  __shared__ float s_ev[384][3];
  __shared__ int s_src[128];
  __shared__ float s_alpha[128][3];
  __shared__ float part[3][512];
  int r0 = rowptr[n], deg = rowptr[n + 1] - r0;
  float adl[3] = {ad1[3 * n], ad1[3 * n + 1], ad1[3 * n + 2]};

  if (tid < 64) {
    float mx[3] = {-1e30f, -1e30f, -1e30f};
    for (int e = tid; e < deg; e += 64) {
      int s = srcp[r0 + e];
      float v0 = as1[3 * s] + adl[0];     v0 = v0 > 0.f ? v0 : 0.2f * v0;
      float v1 = as1[3 * s + 1] + adl[1]; v1 = v1 > 0.f ? v1 : 0.2f * v1;
      float v2 = as1[3 * s + 2] + adl[2]; v2 = v2 > 0.f ? v2 : 0.2f * v2;
      if (e < 384) { s_ev[e][0] = v0; s_ev[e][1] = v1; s_ev[e][2] = v2; }
      mx[0] = fmaxf(mx[0], v0); mx[1] = fmaxf(mx[1], v1); mx[2] = fmaxf(mx[2], v2);
    }
#pragma unroll
    for (int hd = 0; hd < 3; hd++)
      for (int off = 32; off; off >>= 1) mx[hd] = fmaxf(mx[hd], __shfl_xor(mx[hd], off));
    float sd[3] = {0.f, 0.f, 0.f};
    for (int e = tid; e < deg; e += 64) {
      float v0, v1, v2;
      if (e < 384) { v0 = s_ev[e][0]; v1 = s_ev[e][1]; v2 = s_ev[e][2]; }
      else {
        int s = srcp[r0 + e];
        v0 = as1[3 * s] + adl[0];     v0 = v0 > 0.f ? v0 : 0.2f * v0;
        v1 = as1[3 * s + 1] + adl[1]; v1 = v1 > 0.f ? v1 : 0.2f * v1;
        v2 = as1[3 * s + 2] + adl[2]; v2 = v2 > 0.f ? v2 : 0.2f * v2;
      }
      sd[0] += __expf(v0 - mx[0]);
      sd[1] += __expf(v1 - mx[1]);
      sd[2] += __expf(v2 - mx[2]);
    }
#pragma unroll
    for (int hd = 0; hd < 3; hd++)
      for (int off = 32; off; off >>= 1) sd[hd] += __shfl_xor(sd[hd], off);
    if (tid == 0) {
#pragma unroll
      for (int hd = 0; hd < 3; hd++) { sm[hd] = mx[hd]; sden[hd] = sd[hd]; }
    }
  }
  __syncthreads();

  int hd = tid >> 6, lane = tid & 63;
  float a[8];
#pragma unroll
  for (int j = 0; j < 8; j++) a[j] = 0.f;

  for (int base = 0; base < deg; base += 128) {
    int cnt = min(128, deg - base);
    if (tid < cnt) {
      int s = srcp[r0 + base + tid];
      s_src[tid] = s;
      float v0, v1, v2;
      if (base + tid < 384) {
        v0 = s_ev[base + tid][0]; v1 = s_ev[base + tid][1]; v2 = s_ev[base + tid][2];
      } else {
        v0 = as1[3 * s] + adl[0];     v0 = v0 > 0.f ? v0 : 0.2f * v0;
        v1 = as1[3 * s + 1] + adl[1]; v1 = v1 > 0.f ? v1 : 0.2f * v1;
        v2 = as1[3 * s + 2] + adl[2]; v2 = v2 > 0.f ? v2 : 0.2f * v2;
      }
      s_alpha[tid][0] = __expf(v0 - sm[0]) / sden[0];
      s_alpha[tid][1] = __expf(v1 - sm[1]) / sden[1];
      s_alpha[tid][2] = __expf(v2 - sm[2]) / sden[2];
    }
    __syncthreads();
    int e = 0;
    for (; e + 4 <= cnt; e += 4) {           // 4-edge unroll: more loads in flight
      const u16* p0 = h1b + (size_t)s_src[e] * C1 + (hd << 9) + lane * 8;
      const u16* p1 = h1b + (size_t)s_src[e + 1] * C1 + (hd << 9) + lane * 8;
      const u16* p2 = h1b + (size_t)s_src[e + 2] * C1 + (hd << 9) + lane * 8;
      const u16* p3 = h1b + (size_t)s_src[e + 3] * C1 + (hd << 9) + lane * 8;
      s16x8 v0 = *(const s16x8*)p0;
      s16x8 v1 = *(const s16x8*)p1;
      s16x8 v2 = *(const s16x8*)p2;
      s16x8 v3 = *(const s16x8*)p3;
      float al0 = s_alpha[e][hd], al1 = s_alpha[e + 1][hd];
      float al2 = s_alpha[e + 2][hd], al3 = s_alpha[e + 3][hd];
#pragma unroll
      for (int j = 0; j < 8; j++)
        a[j] += al0 * b2f((u16)v0[j]) + al1 * b2f((u16)v1[j])
              + al2 * b2f((u16)v2[j]) + al3 * b2f((u16)v3[j]);
    }
    for (; e < cnt; e++) {
      const u16* p0 = h1b + (size_t)s_src[e] * C1 + (hd << 9) + lane * 8;
      s16x8 v0 = *(const s16x8*)p0;
      float al0 = s_alpha[e][hd];
#pragma unroll
      for (int j = 0; j < 8; j++) a[j] += al0 * b2f((u16)v0[j]);
    }
    __syncthreads();
  }

#pragma unroll
  for (int j = 0; j < 8; j++) part[hd][lane * 8 + j] = a[j];
  __syncthreads();
  if (tid < 128) {
    f32x4 p0 = *(const f32x4*)&part[0][tid * 4];
    f32x4 p1 = *(const f32x4*)&part[1][tid * 4];
    f32x4 p2 = *(const f32x4*)&part[2][tid * 4];
    f32x4 bv = *(const f32x4*)(bias + tid * 4);
    f32x4 o;
#pragma unroll
    for (int j = 0; j < 4; j++) o[j] = (p0[j] + p1[j] + p2[j]) * (1.f / 3.f) + bv[j];
    *(f32x4*)(out + (size_t)n * 512 + tid * 4) = o;
  }
}

// gat2 with LDS score cache (scores gathered once; deg<=192 typical)
__global__ void k_gat2(const float* __restrict__ s2, const float* __restrict__ as2,
                       const float* __restrict__ ad2, const int* __restrict__ rowptr,
                       const int* __restrict__ srcp, const float* __restrict__ bias,
                       float* __restrict__ z) {
  int n = blockIdx.x, tid = threadIdx.x;
  __shared__ float s_ev[192][3];
  __shared__ int s_src[64];
  __shared__ float s_alpha[64][3];
  int r0 = rowptr[n], deg = rowptr[n + 1] - r0;
  float adl[3] = {ad2[3 * n], ad2[3 * n + 1], ad2[3 * n + 2]};

  float mx[3] = {-1e30f, -1e30f, -1e30f};
  for (int e = tid; e < deg; e += 64) {
    int s = srcp[r0 + e];
    float v0 = as2[3 * s] + adl[0];     v0 = v0 > 0.f ? v0 : 0.2f * v0;
    float v1 = as2[3 * s + 1] + adl[1]; v1 = v1 > 0.f ? v1 : 0.2f * v1;
    float v2 = as2[3 * s + 2] + adl[2]; v2 = v2 > 0.f ? v2 : 0.2f * v2;
    if (e < 192) { s_ev[e][0] = v0; s_ev[e][1] = v1; s_ev[e][2] = v2; }
    mx[0] = fmaxf(mx[0], v0); mx[1] = fmaxf(mx[1], v1); mx[2] = fmaxf(mx[2], v2);
  }
#pragma unroll
  for (int hd = 0; hd < 3; hd++)
    for (int off = 32; off; off >>= 1) mx[hd] = fmaxf(mx[hd], __shfl_xor(mx[hd], off));
  float sd[3] = {0.f, 0.f, 0.f};
  for (int e = tid; e < deg; e += 64) {
    float v0, v1, v2;
    if (e < 192) { v0 = s_ev[e][0]; v1 = s_ev[e][1]; v2 = s_ev[e][2]; }
    else {
      int s = srcp[r0 + e];
      v0 = as2[3 * s] + adl[0];     v0 = v0 > 0.f ? v0 : 0.2f * v0;
      v1 = as2[3 * s + 1] + adl[1]; v1 = v1 > 0.f ? v1 : 0.2f * v1;
      v2 = as2[3 * s + 2] + adl[2]; v2 = v2 > 0.f ? v2 : 0.2f * v2;
    }
    sd[0] += __expf(v0 - mx[0]);
    sd[1] += __expf(v1 - mx[1]);
    sd[2] += __expf(v2 - mx[2]);
  }
#pragma unroll
  for (int hd = 0; hd < 3; hd++)
    for (int off = 32; off; off >>= 1) sd[hd] += __shfl_xor(sd[hd], off);

  float acc = 0.f;
  for (int base = 0; base < deg; base += 64) {
    int cnt = min(64, deg - base);
    __syncthreads();
    if (tid < cnt) {
      int s = srcp[r0 + base + tid];
      s_src[tid] = s;
      float v0, v1, v2;
      if (base + tid < 192) {
        v0 = s_ev[base + tid][0]; v1 = s_ev[base + tid][1]; v2 = s_ev[base + tid][2];
      } else {
        v0 = as2[3 * s] + adl[0];     v0 = v0 > 0.f ? v0 : 0.2f * v0;
        v1 = as2[3 * s + 1] + adl[1]; v1 = v1 > 0.f ? v1 : 0.2f * v1;
        v2 = as2[3 * s + 2] + adl[2]; v2 = v2 > 0.f ? v2 : 0.2f * v2;
      }
      s_alpha[tid][0] = __expf(v0 - mx[0]) / sd[0];
      s_alpha[tid][1] = __expf(v1 - mx[1]) / sd[1];
      s_alpha[tid][2] = __expf(v2 - mx[2]) / sd[2];
    }
    __syncthreads();
    if (tid < 50) {
      for (int e = 0; e < cnt; e++) {
        const float* row = s2 + (size_t)s_src[e] * C2;
#pragma unroll
        for (int hd = 0; hd < 3; hd++) acc += s_alpha[e][hd] * row[hd * 50 + tid];
      }
    }
  }
  if (tid < 50) z[(size_t)n * ZZ + tid] = acc * (1.f / 3.f) + bias[tid];
}

// ---------------- BatchNorm (training stats, biased var) -------------------
__global__ void k_colstats3(const float* __restrict__ x, float* __restrict__ gsum,
                            float* __restrict__ gsq, long total, int C) {
  long i = (long)blockIdx.x * blockDim.x + threadIdx.x;
  long st = (long)gridDim.x * blockDim.x;
  int c = (int)(i % C);
  float s = 0.f, q = 0.f;
  for (; i < total; i += st) { float v = x[i]; s += v; q += v * v; }
  atomicAdd(&gsum[c], s);
  atomicAdd(&gsq[c], q);
}

// fused bnfinal+bnrelu for C=512 (scale/shift recomputed from L2-hot sums)
__global__ void k_bnrelu4f(const float* __restrict__ x, const float* __restrict__ gsum,
                           const float* __restrict__ gsq, const float* __restrict__ g,
                           const float* __restrict__ bb, u16* __restrict__ out,
                           long total4, float invN) {
  long i = (long)blockIdx.x * blockDim.x + threadIdx.x;
  long st = (long)gridDim.x * blockDim.x;
  for (; i < total4; i += st) {
    long b = i * 4;
    int c = (int)(b & 511);
    f32x4 v = *(const f32x4*)(x + b);
    f32x4 s = *(const f32x4*)(gsum + c);
    f32x4 qv = *(const f32x4*)(gsq + c);
    f32x4 gg = *(const f32x4*)(g + c);
    f32x4 bv = *(const f32x4*)(bb + c);
    s16x4 o;
#pragma unroll
    for (int j = 0; j < 4; j++) {
      float m = s[j] * invN;
      float var = qv[j] * invN - m * m;
      float sc = gg[j] * rsqrtf(var + 1e-5f);
      float r = (v[j] - m) * sc + bv[j];
      r = r > 0.f ? r : 0.f;
      o[j] = (short)f2b(r);
    }
    *(s16x4*)(out + b) = o;
  }
}

// fused bnfinal + bnrelu + pad for the 50->64 latent (zb)
__global__ void k_bnrelu_padf(const float* __restrict__ x, const float* __restrict__ gsum,
                              const float* __restrict__ gsq, const float* __restrict__ g,
                              const float* __restrict__ bb, u16* __restrict__ out) {
  int i = blockIdx.x * blockDim.x + threadIdx.x;
  if (i >= NN * 64) return;
  int c = i & 63, r = i >> 6;
  float v = 0.f;
  if (c < 50) {
    float m = gsum[c] * (1.0f / NN);
    float var = gsq[c] * (1.0f / NN) - m * m;
    float sc = g[c] * rsqrtf(var + 1e-5f);
    v = (x[r * 50 + c] - m) * sc + bb[c];
    v = v > 0.f ? v : 0.f;
  }
  out[i] = f2b(v);
}

// ---------------------------------------------------------------------------
extern "C" void kernel_launch(void* const* d_in, const int* in_sizes, int n_in,
                              void* d_out, int out_size, void* d_ws, size_t ws_size,
                              hipStream_t stream) {
  (void)in_sizes; (void)n_in; (void)out_size;
  const float* x     = (const float*)d_in[0];
  const void*  ei    = d_in[1];
  const float* W1    = (const float*)d_in[2];
  const float* asrc1 = (const float*)d_in[3];
  const float* adst1 = (const float*)d_in[4];
  const float* b1    = (const float*)d_in[5];
  const float* bn1g  = (const float*)d_in[6];
  const float* bn1b  = (const float*)d_in[7];
  const float* W2    = (const float*)d_in[8];
  const float* asrc2 = (const float*)d_in[9];
  const float* adst2 = (const float*)d_in[10];
  const float* b2    = (const float*)d_in[11];
  const float* bn2g  = (const float*)d_in[12];
  const float* bn2b  = (const float*)d_in[13];
  const float* l1w   = (const float*)d_in[14];
  const float* l1b   = (const float*)d_in[15];
  const float* dbng  = (const float*)d_in[16];
  const float* dbnb  = (const float*)d_in[17];
  const float* l2w   = (const float*)d_in[18];
  const float* l2b   = (const float*)d_in[19];
  float* out = (float*)d_out;
  char* ws = (char*)d_ws;

  size_t off = 0;
  auto alloc = [&](size_t b) { size_t r = off; off += (b + 255) & ~(size_t)255; return r; };
  const size_t oXB  = alloc(120320000);                  // xb [20000][3008]; reused below
  const size_t oH1  = alloc(61440000);                   // h1b [20000][1536]; later db
  const size_t oW1T = alloc((size_t)C1 * KP1 * 2);       // w1T [1536][3072]
  const size_t oAS1 = alloc((size_t)NN * 12), oAD1 = alloc((size_t)NN * 12);
  const size_t oAS2 = alloc((size_t)NN * 12), oAD2 = alloc((size_t)NN * 12);
  const size_t oRP  = alloc((size_t)(NN + 1) * 4);
  const size_t oDEG = alloc((size_t)NN * 4);
  const size_t oSRC = alloc((size_t)ET * 4);
  const size_t oBSUM = alloc(512);
  const size_t oS1 = alloc(2048), oQ1 = alloc(2048);
  const size_t oS2 = alloc(2048), oQ2 = alloc(2048);
  const size_t oS3 = alloc(2048), oQ3 = alloc(2048);
  if (ws_size < off) return;

  u16*   xb   = (u16*)(ws + oXB);                        // [20000][3008]
  float* g1   = (float*)(ws + oXB);
  u16*   h2b  = (u16*)(ws + oXB + 40960000);
  float* s2   = (float*)(ws + oXB + 61440000);
  float* zf   = (float*)(ws + oXB + 73440000);
  u16*   zb   = (u16*)(ws + oXB + 77440000);
  u16*   w2T  = (u16*)(ws + oXB + 80000000);
  u16*   l1wT = (u16*)(ws + oXB + 80262400);
  u16*   l2wT = (u16*)(ws + oXB + 80328192);
  float* dbuf = (float*)(ws + oXB);
  u16*   h1b  = (u16*)(ws + oH1);
  u16*   db   = (u16*)(ws + oH1);
  u16*   w1T  = (u16*)(ws + oW1T);
  int* bsum   = (int*)(ws + oBSUM);
  int* deg    = (int*)(ws + oDEG);
  int* rowptr = (int*)(ws + oRP);
  int* srcp   = (int*)(ws + oSRC);
  float *as1 = (float*)(ws + oAS1), *ad1 = (float*)(ws + oAD1);
  float *as2 = (float*)(ws + oAS2), *ad2 = (float*)(ws + oAD2);
  float *sum1 = (float*)(ws + oS1), *sq1 = (float*)(ws + oQ1);
  float *sum2 = (float*)(ws + oS2), *sq2 = (float*)(ws + oQ2);
  float *sum3 = (float*)(ws + oS3), *sq3 = (float*)(ws + oQ3);

  // --- CSR by dst (with self loops) ---
  hipMemsetAsync(deg, 0, (size_t)NN * 4, stream);
  k_deg<<<512, 256, 0, stream>>>(ei, deg);
  k_scan_blk<<<79, 256, 0, stream>>>(deg, rowptr, bsum);   // also zeroes deg
  k_scan_top<<<1, 128, 0, stream>>>(bsum, 79);
  k_scan_add<<<79, 256, 0, stream>>>(rowptr, bsum);
  k_fill<<<512, 256, 0, stream>>>(ei, rowptr, deg, srcp);

  // --- layer 1: GAT(3000 -> 512, 3 heads) ---
  k_cvt_pad4<<<dim3(3, NN), 256, 0, stream>>>(x, xb, NN, DD, KA1);
  k_transpose_tile<<<dim3(C1 / 32, KP1 / 32), 256, 0, stream>>>(W1, w1T, DD, C1, KP1);
  k_gemm8<true, false><<<dim3(6, 79), 512, 0, stream>>>(xb, w1T, h1b, nullptr,
                                                        NN, C1, KP1, KA1, KP1, C1);
  k_attdot1b<<<NN, 192, 0, stream>>>(h1b, asrc1, adst1, as1, ad1, sum1, sq1);
  k_gat1<<<NN, 192, 0, stream>>>(h1b, as1, ad1, rowptr, srcp, b1, g1);
  k_colstats3<<<512, 256, 0, stream>>>(g1, sum1, sq1, (long)NN * HH, HH);
  k_bnrelu4f<<<2048, 256, 0, stream>>>(g1, sum1, sq1, bn1g, bn1b, h2b,
                                       (long)NN * HH / 4, 1.0f / NN);

  // --- layer 2: GAT(512 -> 50, 3 heads) ---
  k_transpose_cvt2<<<256, 256, 0, stream>>>(W2, w2T, HH, C2, 256, HH);
  k_gemm3<false, false><<<dim3(2, 157), 256, 0, stream>>>(h2b, w2T, s2, nullptr,
                                                          NN, C2, HH, HH, C2);
  k_attdot2<<<NN, 64, 0, stream>>>(s2, asrc2, adst2, as2, ad2, sum2, sq2, sum3, sq3);
  k_gat2<<<NN, 64, 0, stream>>>(s2, as2, ad2, rowptr, srcp, b2, zf);
  k_colstats3<<<25, 256, 0, stream>>>(zf, sum2, sq2, (long)NN * ZZ, ZZ);
  k_bnrelu_padf<<<5000, 256, 0, stream>>>(zf, sum2, sq2, bn2g, bn2b, zb);

  // --- decoder ---
  k_cvt_pad4<<<dim3(1, HH), 256, 0, stream>>>(l1w, l1wT, HH, ZZ, 64);      // B^T=[512][64]
  k_gemm3<false, false><<<dim3(4, 157), 256, 0, stream>>>(zb, l1wT, dbuf, l1b,
                                                          NN, HH, 64, 64, HH);
  k_colstats3<<<512, 256, 0, stream>>>(dbuf, sum3, sq3, (long)NN * HH, HH);
  k_bnrelu4f<<<2048, 256, 0, stream>>>(dbuf, sum3, sq3, dbng, dbnb, db,
                                       (long)NN * HH / 4, 1.0f / NN);
  k_cvt_pad4<<<dim3(1, 3072), 256, 0, stream>>>(l2w, l2wT, DD, HH, HH);    // B^T=[3072][512]
  k_gemm8<false, true><<<dim3(12, 79), 512, 0, stream>>>(db, l2wT, out, l2b,
                                                         NN, DD, 512, HH, HH, DD);
}